// Round 2
// baseline (1397.142 us; speedup 1.0000x reference)
//
#include <hip/hip_runtime.h>

#define NODES 100000
#define NEDGE 1600000

// ---------------------------------------------------------------- CSR build

static __global__ void zero_int_kernel(int* __restrict__ p, int n) {
    int i = blockIdx.x * blockDim.x + threadIdx.x;
    int stride = gridDim.x * blockDim.x;
    for (; i < n; i += stride) p[i] = 0;
}

static __global__ void count_deg_kernel(const int* __restrict__ dst, int* __restrict__ deg) {
    int i = blockIdx.x * blockDim.x + threadIdx.x;
    int stride = gridDim.x * blockDim.x;
    for (int e = i; e < NEDGE; e += stride)
        atomicAdd(&deg[dst[e]], 1);
}

// Single-block exclusive scan of deg[NODES] -> row_ptr / cursor.
// deg aliases cursor (read-before-write per element, same thread).
static __global__ __launch_bounds__(1024) void scan_kernel(
    const int* __restrict__ deg, int* __restrict__ row_ptr, int* cursor) {
    __shared__ int part[1024];
    int t = threadIdx.x;
    const int seg = (NODES + 1023) >> 10;  // 98
    int lo = t * seg;
    int hi = min(lo + seg, NODES);
    int s = 0;
    for (int i = lo; i < hi; ++i) s += deg[i];
    part[t] = s;
    __syncthreads();
    for (int off = 1; off < 1024; off <<= 1) {
        int v = (t >= off) ? part[t - off] : 0;
        __syncthreads();
        part[t] += v;
        __syncthreads();
    }
    int run = part[t] - s;  // exclusive prefix
    for (int i = lo; i < hi; ++i) {
        int d = deg[i];
        row_ptr[i] = run;
        cursor[i] = run;
        run += d;
    }
    if (lo < NODES && hi == NODES) row_ptr[NODES] = run;
}

static __global__ void build_csr_kernel(const int* __restrict__ src, const int* __restrict__ dst,
                                        int* __restrict__ cursor, int* __restrict__ col) {
    int i = blockIdx.x * blockDim.x + threadIdx.x;
    int stride = gridDim.x * blockDim.x;
    for (int e = i; e < NEDGE; e += stride) {
        int pos = atomicAdd(&cursor[dst[e]], 1);
        col[pos] = src[e];
    }
}

// -------------------------------------------------- mean-aggregate (D=128)
// OUT[i] = mean_{c in row i} SRC[c].  One 64-lane wave per node, float2/lane.

static __global__ __launch_bounds__(256) void mean_gather128_kernel(
    const float* __restrict__ SRC, const int* __restrict__ row_ptr,
    const int* __restrict__ col, float* __restrict__ OUT) {
    int node = (int)((blockIdx.x * 256 + threadIdx.x) >> 6);
    int lane = threadIdx.x & 63;
    if (node >= NODES) return;
    int s = row_ptr[node];
    int e = row_ptr[node + 1];
    float inv = 1.0f / (float)max(e - s, 1);
    float ax = 0.f, ay = 0.f;
    for (int p = s; p < e; ++p) {
        int c = col[p];
        float2 v = *(const float2*)(SRC + (size_t)c * 128 + lane * 2);
        ax += v.x;
        ay += v.y;
    }
    *(float2*)(OUT + (size_t)node * 128 + lane * 2) = make_float2(ax * inv, ay * inv);
}

// ---------------------------------------------- layer-1 dual-input GEMM
// OUT = relu(X1 @ Wl + bias + X2 @ Wr), all [*,128].  OUT may alias X1:
// each block stages its 64 rows of X1 into LDS before writing them back.
// Two phases share one 32 KB LDS tile.

static __global__ __launch_bounds__(256) void layer1_gemm_kernel(
    const float* X1, const float* __restrict__ X2,
    const float* __restrict__ Wl, const float* __restrict__ Wr,
    const float* __restrict__ bias, float* OUT) {
    __shared__ float sX[64][128];
    const int tid = threadIdx.x;
    const int row0 = blockIdx.x * 64;
    const int tx = tid & 31;
    const int ty = tid >> 5;   // 0..7
    const int jc = tx * 4;
    const int n0 = ty * 8;

    float acc[8][4];
#pragma unroll
    for (int n = 0; n < 8; ++n)
#pragma unroll
        for (int j = 0; j < 4; ++j) acc[n][j] = 0.f;

    for (int phase = 0; phase < 2; ++phase) {
        const float* X = phase ? X2 : X1;
        const float* W = phase ? Wr : Wl;
        if (phase) __syncthreads();  // phase-0 LDS reads complete before restage
#pragma unroll
        for (int p = 0; p < 8; ++p) {
            int idx = tid + p * 256;
            int r = idx >> 5;
            int c4 = (idx & 31) << 2;
            int row = row0 + r;
            float4 v = make_float4(0.f, 0.f, 0.f, 0.f);
            if (row < NODES) v = *(const float4*)(X + (size_t)row * 128 + c4);
            *(float4*)(&sX[r][c4]) = v;
        }
        __syncthreads();
        for (int k = 0; k < 128; ++k) {
            float4 w = *(const float4*)(W + k * 128 + jc);
#pragma unroll
            for (int n = 0; n < 8; ++n) {
                float a = sX[n0 + n][k];
                acc[n][0] += a * w.x;
                acc[n][1] += a * w.y;
                acc[n][2] += a * w.z;
                acc[n][3] += a * w.w;
            }
        }
    }

    float4 b = *(const float4*)(bias + jc);
#pragma unroll
    for (int n = 0; n < 8; ++n) {
        int row = row0 + n0 + n;
        if (row < NODES) {
            float4 o;
            o.x = fmaxf(acc[n][0] + b.x, 0.f);
            o.y = fmaxf(acc[n][1] + b.y, 0.f);
            o.z = fmaxf(acc[n][2] + b.z, 0.f);
            o.w = fmaxf(acc[n][3] + b.w, 0.f);
            *(float4*)(OUT + (size_t)row * 128 + jc) = o;
        }
    }
}

// ---------------------------------------------- layer-2 fused agg+GEMM
// out_i = (mean_j H_j) @ W2l + b2 + H_i @ W2r.   One wave per node
// (grid-stride).  W2l/W2r staged in 64 KB LDS; the per-node 128-vectors
// (neighbor mean + own row) are broadcast across lanes via shfl.

static __global__ __launch_bounds__(256) void layer2_fused_kernel(
    const float* __restrict__ H, const float* __restrict__ W2l,
    const float* __restrict__ W2r, const float* __restrict__ b2,
    const int* __restrict__ row_ptr, const int* __restrict__ col,
    float* __restrict__ OUT) {
    __shared__ float sWl[128 * 64];
    __shared__ float sWr[128 * 64];
    for (int i = threadIdx.x; i < (128 * 64) / 4; i += 256) {
        ((float4*)sWl)[i] = ((const float4*)W2l)[i];
        ((float4*)sWr)[i] = ((const float4*)W2r)[i];
    }
    __syncthreads();

    const int lane = threadIdx.x & 63;
    const int wave0 = (int)((blockIdx.x * 256 + threadIdx.x) >> 6);
    const int nwaves = (int)((gridDim.x * 256) >> 6);
    const float bias = b2[lane];

    for (int node = wave0; node < NODES; node += nwaves) {
        int s = row_ptr[node];
        int e = row_ptr[node + 1];
        float inv = 1.0f / (float)max(e - s, 1);
        float sx = 0.f, sy = 0.f;
        for (int p = s; p < e; ++p) {
            int c = col[p];
            float2 v = *(const float2*)(H + (size_t)c * 128 + lane * 2);
            sx += v.x;
            sy += v.y;
        }
        sx *= inv;
        sy *= inv;
        float2 hv = *(const float2*)(H + (size_t)node * 128 + lane * 2);

        float acc = bias;
#pragma unroll 4
        for (int l2 = 0; l2 < 64; ++l2) {
            float m0 = __shfl(sx, l2);
            float m1 = __shfl(sy, l2);
            float h0 = __shfl(hv.x, l2);
            float h1 = __shfl(hv.y, l2);
            int k0 = 2 * l2;
            acc += m0 * sWl[k0 * 64 + lane] + h0 * sWr[k0 * 64 + lane];
            acc += m1 * sWl[(k0 + 1) * 64 + lane] + h1 * sWr[(k0 + 1) * 64 + lane];
        }
        OUT[(size_t)node * 64 + lane] = acc;
    }
}

// ---------------------------------------------------------------- launch

extern "C" void kernel_launch(void* const* d_in, const int* in_sizes, int n_in,
                              void* d_out, int out_size, void* d_ws, size_t ws_size,
                              hipStream_t stream) {
    const float* x   = (const float*)d_in[0];
    const float* W1l = (const float*)d_in[1];
    const float* b1  = (const float*)d_in[2];
    const float* W1r = (const float*)d_in[3];
    const float* W2l = (const float*)d_in[4];
    const float* b2  = (const float*)d_in[5];
    const float* W2r = (const float*)d_in[6];
    const int*   ei  = (const int*)d_in[7];
    const int* esrc = ei;          // edge_index[0]
    const int* edst = ei + NEDGE;  // edge_index[1]
    float* out = (float*)d_out;

    // ws layout — total 58,400,256 B (~55.7 MiB), half of R1's footprint.
    char* ws = (char*)d_ws;
    size_t off = 0;
    int* row_ptr = (int*)(ws + off); off += (((size_t)(NODES + 1) * 4) + 255) & ~(size_t)255;
    int* cursor  = (int*)(ws + off); off += (((size_t)NODES * 4) + 255) & ~(size_t)255;
    int* col     = (int*)(ws + off); off += (size_t)NEDGE * 4;
    float* A     = (float*)(ws + off); off += (size_t)NODES * 128 * 4;  // mean_x, then h in place

    // ---- CSR build
    zero_int_kernel<<<256, 256, 0, stream>>>(cursor, NODES);
    count_deg_kernel<<<2048, 256, 0, stream>>>(edst, cursor);
    scan_kernel<<<1, 1024, 0, stream>>>(cursor, row_ptr, cursor);
    build_csr_kernel<<<2048, 256, 0, stream>>>(esrc, edst, cursor, col);

    // ---- layer 1: A = mean_agg(x); A = relu(A@W1l + b1 + x@W1r) in place
    mean_gather128_kernel<<<(NODES * 64 + 255) / 256, 256, 0, stream>>>(x, row_ptr, col, A);
    layer1_gemm_kernel<<<(NODES + 63) / 64, 256, 0, stream>>>(A, x, W1l, W1r, b1, A);

    // ---- layer 2 fused: out = mean_agg(A)@W2l + b2 + A@W2r
    layer2_fused_kernel<<<2048, 256, 0, stream>>>(A, W2l, W2r, b2, row_ptr, col, out);
}

// Round 3
// 919.180 us; speedup vs baseline: 1.5200x; 1.5200x over previous
//
#include <hip/hip_runtime.h>

#define NODES 100000
#define NEDGE 1600000

// ------------------------------------------------------------ bf16 helpers

static __device__ __forceinline__ unsigned short f2bf(float x) {
    union { float f; unsigned int u; } v; v.f = x;
    unsigned int r = (v.u + 0x7fffu + ((v.u >> 16) & 1u)) >> 16;  // RNE
    return (unsigned short)r;
}
static __device__ __forceinline__ unsigned int packbf2(float a, float b) {
    return (unsigned int)f2bf(a) | ((unsigned int)f2bf(b) << 16);
}
static __device__ __forceinline__ float2 unpackbf2(unsigned int u) {
    union { unsigned int u; float f; } a, b;
    a.u = u << 16; b.u = u & 0xffff0000u;
    return make_float2(a.f, b.f);
}

// ---------------------------------------------------------------- CSR build

static __global__ void zero_int_kernel(int* __restrict__ p, int n) {
    int i = blockIdx.x * blockDim.x + threadIdx.x;
    int stride = gridDim.x * blockDim.x;
    for (; i < n; i += stride) p[i] = 0;
}

static __global__ void count_deg_kernel(const int* __restrict__ dst, int* __restrict__ deg) {
    int i = blockIdx.x * blockDim.x + threadIdx.x;
    int stride = gridDim.x * blockDim.x;
    for (int e = i; e < NEDGE; e += stride)
        atomicAdd(&deg[dst[e]], 1);
}

static __global__ __launch_bounds__(1024) void scan_kernel(
    const int* __restrict__ deg, int* __restrict__ row_ptr, int* cursor) {
    __shared__ int part[1024];
    int t = threadIdx.x;
    const int seg = (NODES + 1023) >> 10;  // 98
    int lo = t * seg;
    int hi = min(lo + seg, NODES);
    int s = 0;
    for (int i = lo; i < hi; ++i) s += deg[i];
    part[t] = s;
    __syncthreads();
    for (int off = 1; off < 1024; off <<= 1) {
        int v = (t >= off) ? part[t - off] : 0;
        __syncthreads();
        part[t] += v;
        __syncthreads();
    }
    int run = part[t] - s;  // exclusive prefix
    for (int i = lo; i < hi; ++i) {
        int d = deg[i];
        row_ptr[i] = run;
        cursor[i] = run;
        run += d;
    }
    if (lo < NODES && hi == NODES) row_ptr[NODES] = run;
}

static __global__ void build_csr_kernel(const int* __restrict__ src, const int* __restrict__ dst,
                                        int* __restrict__ cursor, int* __restrict__ col) {
    int i = blockIdx.x * blockDim.x + threadIdx.x;
    int stride = gridDim.x * blockDim.x;
    for (int e = i; e < NEDGE; e += stride) {
        int pos = atomicAdd(&cursor[dst[e]], 1);
        col[pos] = src[e];
    }
}

// -------------------------------------------------- layer-1 dual GEMM
// U = bf16(X @ W1l), V = bf16(X @ W1r + b1).  X fp32 [N,128].
// 64-node tile, 256 threads, 8 rows x 4 cols per thread.

static __global__ __launch_bounds__(256) void gemm1_dual_kernel(
    const float* __restrict__ X, const float* __restrict__ Wl,
    const float* __restrict__ Wr, const float* __restrict__ b1,
    unsigned int* __restrict__ U32, unsigned int* __restrict__ V32) {
    __shared__ float sX[128][65];  // k-major
    const int tid = threadIdx.x;
    const int row0 = blockIdx.x * 64;

    {   // stage 64 rows x 128 cols, transposed
        int c4 = (tid & 31) * 4;
        int r0 = tid >> 5;
#pragma unroll
        for (int p = 0; p < 8; ++p) {
            int r = r0 + p * 8;
            int row = row0 + r;
            float4 v4 = make_float4(0.f, 0.f, 0.f, 0.f);
            if (row < NODES) v4 = *(const float4*)(X + (size_t)row * 128 + c4);
            sX[c4 + 0][r] = v4.x;
            sX[c4 + 1][r] = v4.y;
            sX[c4 + 2][r] = v4.z;
            sX[c4 + 3][r] = v4.w;
        }
    }
    __syncthreads();

    const int tx = tid & 31;
    const int ty = tid >> 5;   // 0..7
    const int jc = tx * 4;
    const int n0 = ty * 8;

    float accU[8][4], accV[8][4];
#pragma unroll
    for (int n = 0; n < 8; ++n)
#pragma unroll
        for (int j = 0; j < 4; ++j) { accU[n][j] = 0.f; accV[n][j] = 0.f; }

    for (int k = 0; k < 128; ++k) {
        float4 wl = *(const float4*)(Wl + k * 128 + jc);
        float4 wr = *(const float4*)(Wr + k * 128 + jc);
        float a[8];
#pragma unroll
        for (int n = 0; n < 8; ++n) a[n] = sX[k][n0 + n];
#pragma unroll
        for (int n = 0; n < 8; ++n) {
            accU[n][0] += a[n] * wl.x;
            accU[n][1] += a[n] * wl.y;
            accU[n][2] += a[n] * wl.z;
            accU[n][3] += a[n] * wl.w;
            accV[n][0] += a[n] * wr.x;
            accV[n][1] += a[n] * wr.y;
            accV[n][2] += a[n] * wr.z;
            accV[n][3] += a[n] * wr.w;
        }
    }

    float4 b = *(const float4*)(b1 + jc);
#pragma unroll
    for (int n = 0; n < 8; ++n) {
        int row = row0 + n0 + n;
        if (row < NODES) {
            uint2 uu, vv;
            uu.x = packbf2(accU[n][0], accU[n][1]);
            uu.y = packbf2(accU[n][2], accU[n][3]);
            vv.x = packbf2(accV[n][0] + b.x, accV[n][1] + b.y);
            vv.y = packbf2(accV[n][2] + b.z, accV[n][3] + b.w);
            *(uint2*)&U32[(size_t)row * 64 + tx * 2] = uu;
            *(uint2*)&V32[(size_t)row * 64 + tx * 2] = vv;
        }
    }
}

// -------------------------------------------------- layer-1 aggregate
// H[i] = bf16( relu( mean_{c in row i} U[c] + V[i] ) ).  H aliases V
// (element-wise in place, same thread reads then writes).  One wave/node,
// one uint (2 bf16 features) per lane -> one 256 B row read per edge.

static __global__ __launch_bounds__(256) void agg1_kernel(
    const unsigned int* __restrict__ U32, const int* __restrict__ row_ptr,
    const int* __restrict__ col, unsigned int* __restrict__ H32) {
    int node = (int)((blockIdx.x * 256 + threadIdx.x) >> 6);
    int lane = threadIdx.x & 63;
    if (node >= NODES) return;
    int s = row_ptr[node];
    int e = row_ptr[node + 1];
    float inv = 1.0f / (float)max(e - s, 1);
    float ax = 0.f, ay = 0.f;
    for (int p = s; p < e; ++p) {
        float2 v = unpackbf2(U32[(size_t)col[p] * 64 + lane]);
        ax += v.x;
        ay += v.y;
    }
    float2 vv = unpackbf2(H32[(size_t)node * 64 + lane]);
    float ox = fmaxf(ax * inv + vv.x, 0.f);
    float oy = fmaxf(ay * inv + vv.y, 0.f);
    H32[(size_t)node * 64 + lane] = packbf2(ox, oy);
}

// -------------------------------------------------- layer-2 dual GEMM
// T = bf16(H @ W2l), OUT = H @ W2r + b2 (fp32, direct to d_out).
// H bf16 [N,128].  64-node tile, 256 threads, 4 rows x 4 cols per thread.

static __global__ __launch_bounds__(256) void gemm2_dual_kernel(
    const unsigned int* __restrict__ H32, const float* __restrict__ W2l,
    const float* __restrict__ W2r, const float* __restrict__ b2,
    unsigned int* __restrict__ T32, float* __restrict__ OUT) {
    __shared__ unsigned int sH[64][65];  // row-major, packed bf16 pairs
    const int tid = threadIdx.x;
    const int row0 = blockIdx.x * 64;

#pragma unroll
    for (int p = 0; p < 4; ++p) {
        int gi = tid + p * 256;       // uint4 id in [0,1024)
        int r = gi >> 4;
        int c4 = (gi & 15) * 4;
        int row = row0 + r;
        uint4 v = make_uint4(0u, 0u, 0u, 0u);
        if (row < NODES) v = *(const uint4*)&H32[(size_t)row * 64 + c4];
        sH[r][c4 + 0] = v.x;
        sH[r][c4 + 1] = v.y;
        sH[r][c4 + 2] = v.z;
        sH[r][c4 + 3] = v.w;
    }
    __syncthreads();

    const int tx = tid & 15;
    const int ty = tid >> 4;   // 0..15
    const int jc = tx * 4;
    const int n0 = ty * 4;

    float accU[4][4], accV[4][4];
#pragma unroll
    for (int n = 0; n < 4; ++n)
#pragma unroll
        for (int j = 0; j < 4; ++j) { accU[n][j] = 0.f; accV[n][j] = 0.f; }

    for (int k2 = 0; k2 < 64; ++k2) {
        float4 wl0 = *(const float4*)(W2l + (2 * k2 + 0) * 64 + jc);
        float4 wl1 = *(const float4*)(W2l + (2 * k2 + 1) * 64 + jc);
        float4 wr0 = *(const float4*)(W2r + (2 * k2 + 0) * 64 + jc);
        float4 wr1 = *(const float4*)(W2r + (2 * k2 + 1) * 64 + jc);
#pragma unroll
        for (int n = 0; n < 4; ++n) {
            float2 a = unpackbf2(sH[n0 + n][k2]);
            accU[n][0] += a.x * wl0.x + a.y * wl1.x;
            accU[n][1] += a.x * wl0.y + a.y * wl1.y;
            accU[n][2] += a.x * wl0.z + a.y * wl1.z;
            accU[n][3] += a.x * wl0.w + a.y * wl1.w;
            accV[n][0] += a.x * wr0.x + a.y * wr1.x;
            accV[n][1] += a.x * wr0.y + a.y * wr1.y;
            accV[n][2] += a.x * wr0.z + a.y * wr1.z;
            accV[n][3] += a.x * wr0.w + a.y * wr1.w;
        }
    }

    float4 b = *(const float4*)(b2 + jc);
#pragma unroll
    for (int n = 0; n < 4; ++n) {
        int row = row0 + n0 + n;
        if (row < NODES) {
            uint2 t;
            t.x = packbf2(accU[n][0], accU[n][1]);
            t.y = packbf2(accU[n][2], accU[n][3]);
            *(uint2*)&T32[(size_t)row * 32 + tx * 2] = t;
            float4 r = make_float4(accV[n][0] + b.x, accV[n][1] + b.y,
                                   accV[n][2] + b.z, accV[n][3] + b.w);
            *(float4*)(OUT + (size_t)row * 64 + jc) = r;
        }
    }
}

// -------------------------------------------------- layer-2 aggregate
// OUT[i] += mean_{c in row i} T[c].  Half-wave (32 lanes) per node, one
// uint (2 bf16) per lane -> one 128 B line per edge.  In-place elementwise.

static __global__ __launch_bounds__(256) void agg2_kernel(
    const unsigned int* __restrict__ T32, const int* __restrict__ row_ptr,
    const int* __restrict__ col, float* __restrict__ OUT) {
    int node = (int)((blockIdx.x * 256 + threadIdx.x) >> 5);
    int l = threadIdx.x & 31;
    if (node >= NODES) return;
    int s = row_ptr[node];
    int e = row_ptr[node + 1];
    float inv = 1.0f / (float)max(e - s, 1);
    float ax = 0.f, ay = 0.f;
    for (int p = s; p < e; ++p) {
        float2 v = unpackbf2(T32[(size_t)col[p] * 32 + l]);
        ax += v.x;
        ay += v.y;
    }
    float2 o = *(float2*)(OUT + (size_t)node * 64 + l * 2);
    o.x += ax * inv;
    o.y += ay * inv;
    *(float2*)(OUT + (size_t)node * 64 + l * 2) = o;
}

// ---------------------------------------------------------------- launch

extern "C" void kernel_launch(void* const* d_in, const int* in_sizes, int n_in,
                              void* d_out, int out_size, void* d_ws, size_t ws_size,
                              hipStream_t stream) {
    const float* x   = (const float*)d_in[0];
    const float* W1l = (const float*)d_in[1];
    const float* b1  = (const float*)d_in[2];
    const float* W1r = (const float*)d_in[3];
    const float* W2l = (const float*)d_in[4];
    const float* b2  = (const float*)d_in[5];
    const float* W2r = (const float*)d_in[6];
    const int*   ei  = (const int*)d_in[7];
    const int* esrc = ei;          // edge_index[0]
    const int* edst = ei + NEDGE;  // edge_index[1]
    float* out = (float*)d_out;

    // ws layout — 58.0 MB total (within R2's proven 58.4 MB footprint).
    char* ws = (char*)d_ws;
    size_t off = 0;
    int* row_ptr = (int*)(ws + off); off += (((size_t)(NODES + 1) * 4) + 255) & ~(size_t)255;
    int* col     = (int*)(ws + off); off += (size_t)NEDGE * 4;
    unsigned int* U32 = (unsigned int*)(ws + off); off += (size_t)NODES * 128 * 2;  // u bf16; later t
    unsigned int* V32 = (unsigned int*)(ws + off); off += (size_t)NODES * 128 * 2;  // v bf16; then h in place
    // cursor aliases U's space: CSR build completes before gemm1 writes U.
    int* cursor = (int*)U32;
    // T (bf16 [N,64] = 12.8 MB) aliases U's space: U dead after agg1.
    unsigned int* T32 = U32;

    // ---- CSR build
    zero_int_kernel<<<256, 256, 0, stream>>>(cursor, NODES);
    count_deg_kernel<<<2048, 256, 0, stream>>>(edst, cursor);
    scan_kernel<<<1, 1024, 0, stream>>>(cursor, row_ptr, cursor);
    build_csr_kernel<<<2048, 256, 0, stream>>>(esrc, edst, cursor, col);

    const int gemm_grid = (NODES + 63) / 64;  // 1563

    // ---- layer 1
    gemm1_dual_kernel<<<gemm_grid, 256, 0, stream>>>(x, W1l, W1r, b1, U32, V32);
    agg1_kernel<<<(NODES + 3) / 4, 256, 0, stream>>>(U32, row_ptr, col, V32);

    // ---- layer 2 (H = V32 in place)
    gemm2_dual_kernel<<<gemm_grid, 256, 0, stream>>>(V32, W2l, W2r, b2, T32, out);
    agg2_kernel<<<(NODES + 7) / 8, 256, 0, stream>>>(T32, row_ptr, col, out);
}

// Round 4
// 580.452 us; speedup vs baseline: 2.4070x; 1.5836x over previous
//
#include <hip/hip_runtime.h>

#define NODES 100000
#define NEDGE 1600000
#define SCHUNK 1024
#define SBLOCKS ((NODES + SCHUNK - 1) / SCHUNK)  // 98

// ------------------------------------------------------------ bf16 helpers

static __device__ __forceinline__ unsigned short f2bf(float x) {
    union { float f; unsigned int u; } v; v.f = x;
    unsigned int r = (v.u + 0x7fffu + ((v.u >> 16) & 1u)) >> 16;  // RNE
    return (unsigned short)r;
}
static __device__ __forceinline__ unsigned int packbf2(float a, float b) {
    return (unsigned int)f2bf(a) | ((unsigned int)f2bf(b) << 16);
}
static __device__ __forceinline__ float2 unpackbf2(unsigned int u) {
    union { unsigned int u; float f; } a, b;
    a.u = u << 16; b.u = u & 0xffff0000u;
    return make_float2(a.f, b.f);
}

// ---------------------------------------------------------------- CSR build

static __global__ void zero_int_kernel(int* __restrict__ p, int n) {
    int i = blockIdx.x * blockDim.x + threadIdx.x;
    int stride = gridDim.x * blockDim.x;
    for (; i < n; i += stride) p[i] = 0;
}

static __global__ void count_deg_kernel(const int* __restrict__ dst, int* __restrict__ deg) {
    int i = blockIdx.x * blockDim.x + threadIdx.x;
    int stride = gridDim.x * blockDim.x;
    for (int e = i; e < NEDGE; e += stride)
        atomicAdd(&deg[dst[e]], 1);
}

// Phase A: per-chunk sums.  98 blocks x 256 threads, 4 elems/thread.
static __global__ __launch_bounds__(256) void scan_partial_kernel(
    const int* __restrict__ deg, int* __restrict__ partials) {
    __shared__ int ss[256];
    int t = threadIdx.x;
    int base = blockIdx.x * SCHUNK + t * 4;
    int s = 0;
#pragma unroll
    for (int j = 0; j < 4; ++j) {
        int i = base + j;
        if (i < NODES) s += deg[i];
    }
    ss[t] = s;
    __syncthreads();
    for (int off = 128; off > 0; off >>= 1) {
        if (t < off) ss[t] += ss[t + off];
        __syncthreads();
    }
    if (t == 0) partials[blockIdx.x] = ss[0];
}

// Phase B: scan the 98 partials (1 block, 128 threads); also writes row_ptr[NODES].
static __global__ __launch_bounds__(128) void scan_offsets_kernel(
    const int* __restrict__ partials, int* __restrict__ block_off,
    int* __restrict__ row_ptr) {
    __shared__ int ss[128];
    int t = threadIdx.x;
    int v = (t < SBLOCKS) ? partials[t] : 0;
    ss[t] = v;
    __syncthreads();
    for (int off = 1; off < 128; off <<= 1) {
        int u = (t >= off) ? ss[t - off] : 0;
        __syncthreads();
        ss[t] += u;
        __syncthreads();
    }
    if (t < SBLOCKS) block_off[t] = ss[t] - v;  // exclusive
    if (t == 127) row_ptr[NODES] = ss[127];     // total (= NEDGE)
}

// Phase C: per-chunk exclusive scan + global offset -> row_ptr, cursor.
// cursor may alias deg (per-element read-before-write by the same thread).
static __global__ __launch_bounds__(256) void scan_scatter_kernel(
    const int* deg, const int* __restrict__ block_off,
    int* __restrict__ row_ptr, int* cursor) {
    __shared__ int ss[256];
    int t = threadIdx.x;
    int base = blockIdx.x * SCHUNK + t * 4;
    int d[4];
    int s = 0;
#pragma unroll
    for (int j = 0; j < 4; ++j) {
        int i = base + j;
        d[j] = (i < NODES) ? deg[i] : 0;
        s += d[j];
    }
    ss[t] = s;
    __syncthreads();
    for (int off = 1; off < 256; off <<= 1) {
        int u = (t >= off) ? ss[t - off] : 0;
        __syncthreads();
        ss[t] += u;
        __syncthreads();
    }
    int run = block_off[blockIdx.x] + ss[t] - s;
#pragma unroll
    for (int j = 0; j < 4; ++j) {
        int i = base + j;
        if (i < NODES) {
            row_ptr[i] = run;
            cursor[i] = run;
            run += d[j];
        }
    }
}

static __global__ void build_csr_kernel(const int* __restrict__ src, const int* __restrict__ dst,
                                        int* __restrict__ cursor, int* __restrict__ col) {
    int i = blockIdx.x * blockDim.x + threadIdx.x;
    int stride = gridDim.x * blockDim.x;
    for (int e = i; e < NEDGE; e += stride) {
        int pos = atomicAdd(&cursor[dst[e]], 1);
        col[pos] = src[e];
    }
}

// -------------------------------------------------- layer-1 dual GEMM
// U = bf16(X @ W1l), V = bf16(X @ W1r + b1).  X fp32 [N,128].

static __global__ __launch_bounds__(256) void gemm1_dual_kernel(
    const float* __restrict__ X, const float* __restrict__ Wl,
    const float* __restrict__ Wr, const float* __restrict__ b1,
    unsigned int* __restrict__ U32, unsigned int* __restrict__ V32) {
    __shared__ float sX[128][65];  // k-major
    const int tid = threadIdx.x;
    const int row0 = blockIdx.x * 64;

    {
        int c4 = (tid & 31) * 4;
        int r0 = tid >> 5;
#pragma unroll
        for (int p = 0; p < 8; ++p) {
            int r = r0 + p * 8;
            int row = row0 + r;
            float4 v4 = make_float4(0.f, 0.f, 0.f, 0.f);
            if (row < NODES) v4 = *(const float4*)(X + (size_t)row * 128 + c4);
            sX[c4 + 0][r] = v4.x;
            sX[c4 + 1][r] = v4.y;
            sX[c4 + 2][r] = v4.z;
            sX[c4 + 3][r] = v4.w;
        }
    }
    __syncthreads();

    const int tx = tid & 31;
    const int ty = tid >> 5;
    const int jc = tx * 4;
    const int n0 = ty * 8;

    float accU[8][4], accV[8][4];
#pragma unroll
    for (int n = 0; n < 8; ++n)
#pragma unroll
        for (int j = 0; j < 4; ++j) { accU[n][j] = 0.f; accV[n][j] = 0.f; }

    for (int k = 0; k < 128; ++k) {
        float4 wl = *(const float4*)(Wl + k * 128 + jc);
        float4 wr = *(const float4*)(Wr + k * 128 + jc);
        float a[8];
#pragma unroll
        for (int n = 0; n < 8; ++n) a[n] = sX[k][n0 + n];
#pragma unroll
        for (int n = 0; n < 8; ++n) {
            accU[n][0] += a[n] * wl.x;
            accU[n][1] += a[n] * wl.y;
            accU[n][2] += a[n] * wl.z;
            accU[n][3] += a[n] * wl.w;
            accV[n][0] += a[n] * wr.x;
            accV[n][1] += a[n] * wr.y;
            accV[n][2] += a[n] * wr.z;
            accV[n][3] += a[n] * wr.w;
        }
    }

    float4 b = *(const float4*)(b1 + jc);
#pragma unroll
    for (int n = 0; n < 8; ++n) {
        int row = row0 + n0 + n;
        if (row < NODES) {
            uint2 uu, vv;
            uu.x = packbf2(accU[n][0], accU[n][1]);
            uu.y = packbf2(accU[n][2], accU[n][3]);
            vv.x = packbf2(accV[n][0] + b.x, accV[n][1] + b.y);
            vv.y = packbf2(accV[n][2] + b.z, accV[n][3] + b.w);
            *(uint2*)&U32[(size_t)row * 64 + tx * 2] = uu;
            *(uint2*)&V32[(size_t)row * 64 + tx * 2] = vv;
        }
    }
}

// -------------------------------------------------- layer-1 aggregate
// H[i] = bf16(relu(mean_j U[j] + V[i])), in place over V.  One wave/node,
// edge loop unrolled x4 with loads grouped for MLP.

static __global__ __launch_bounds__(256) void agg1_kernel(
    const unsigned int* __restrict__ U32, const int* __restrict__ row_ptr,
    const int* __restrict__ col, unsigned int* __restrict__ H32) {
    int node = (int)((blockIdx.x * 256 + threadIdx.x) >> 6);
    int lane = threadIdx.x & 63;
    if (node >= NODES) return;
    int s = row_ptr[node];
    int e = row_ptr[node + 1];
    float inv = 1.0f / (float)max(e - s, 1);
    float ax = 0.f, ay = 0.f;
    int p = s;
    for (; p + 3 < e; p += 4) {
        int c0 = col[p], c1 = col[p + 1], c2 = col[p + 2], c3 = col[p + 3];
        unsigned int u0 = U32[(size_t)c0 * 64 + lane];
        unsigned int u1 = U32[(size_t)c1 * 64 + lane];
        unsigned int u2 = U32[(size_t)c2 * 64 + lane];
        unsigned int u3 = U32[(size_t)c3 * 64 + lane];
        float2 v0 = unpackbf2(u0), v1 = unpackbf2(u1);
        float2 v2 = unpackbf2(u2), v3 = unpackbf2(u3);
        ax += (v0.x + v1.x) + (v2.x + v3.x);
        ay += (v0.y + v1.y) + (v2.y + v3.y);
    }
    for (; p < e; ++p) {
        float2 v = unpackbf2(U32[(size_t)col[p] * 64 + lane]);
        ax += v.x;
        ay += v.y;
    }
    float2 vv = unpackbf2(H32[(size_t)node * 64 + lane]);
    float ox = fmaxf(ax * inv + vv.x, 0.f);
    float oy = fmaxf(ay * inv + vv.y, 0.f);
    H32[(size_t)node * 64 + lane] = packbf2(ox, oy);
}

// -------------------------------------------------- layer-2 dual GEMM
// T = bf16(H @ W2l), OUT = H @ W2r + b2 (fp32, direct to d_out).

static __global__ __launch_bounds__(256) void gemm2_dual_kernel(
    const unsigned int* __restrict__ H32, const float* __restrict__ W2l,
    const float* __restrict__ W2r, const float* __restrict__ b2,
    unsigned int* __restrict__ T32, float* __restrict__ OUT) {
    __shared__ unsigned int sH[64][65];
    const int tid = threadIdx.x;
    const int row0 = blockIdx.x * 64;

#pragma unroll
    for (int p = 0; p < 4; ++p) {
        int gi = tid + p * 256;
        int r = gi >> 4;
        int c4 = (gi & 15) * 4;
        int row = row0 + r;
        uint4 v = make_uint4(0u, 0u, 0u, 0u);
        if (row < NODES) v = *(const uint4*)&H32[(size_t)row * 64 + c4];
        sH[r][c4 + 0] = v.x;
        sH[r][c4 + 1] = v.y;
        sH[r][c4 + 2] = v.z;
        sH[r][c4 + 3] = v.w;
    }
    __syncthreads();

    const int tx = tid & 15;
    const int ty = tid >> 4;
    const int jc = tx * 4;
    const int n0 = ty * 4;

    float accU[4][4], accV[4][4];
#pragma unroll
    for (int n = 0; n < 4; ++n)
#pragma unroll
        for (int j = 0; j < 4; ++j) { accU[n][j] = 0.f; accV[n][j] = 0.f; }

    for (int k2 = 0; k2 < 64; ++k2) {
        float4 wl0 = *(const float4*)(W2l + (2 * k2 + 0) * 64 + jc);
        float4 wl1 = *(const float4*)(W2l + (2 * k2 + 1) * 64 + jc);
        float4 wr0 = *(const float4*)(W2r + (2 * k2 + 0) * 64 + jc);
        float4 wr1 = *(const float4*)(W2r + (2 * k2 + 1) * 64 + jc);
#pragma unroll
        for (int n = 0; n < 4; ++n) {
            float2 a = unpackbf2(sH[n0 + n][k2]);
            accU[n][0] += a.x * wl0.x + a.y * wl1.x;
            accU[n][1] += a.x * wl0.y + a.y * wl1.y;
            accU[n][2] += a.x * wl0.z + a.y * wl1.z;
            accU[n][3] += a.x * wl0.w + a.y * wl1.w;
            accV[n][0] += a.x * wr0.x + a.y * wr1.x;
            accV[n][1] += a.x * wr0.y + a.y * wr1.y;
            accV[n][2] += a.x * wr0.z + a.y * wr1.z;
            accV[n][3] += a.x * wr0.w + a.y * wr1.w;
        }
    }

    float4 b = *(const float4*)(b2 + jc);
#pragma unroll
    for (int n = 0; n < 4; ++n) {
        int row = row0 + n0 + n;
        if (row < NODES) {
            uint2 t;
            t.x = packbf2(accU[n][0], accU[n][1]);
            t.y = packbf2(accU[n][2], accU[n][3]);
            *(uint2*)&T32[(size_t)row * 32 + tx * 2] = t;
            float4 r = make_float4(accV[n][0] + b.x, accV[n][1] + b.y,
                                   accV[n][2] + b.z, accV[n][3] + b.w);
            *(float4*)(OUT + (size_t)row * 64 + jc) = r;
        }
    }
}

// -------------------------------------------------- layer-2 aggregate
// OUT[i] += mean_j T[j].  Half-wave per node, unrolled x4.

static __global__ __launch_bounds__(256) void agg2_kernel(
    const unsigned int* __restrict__ T32, const int* __restrict__ row_ptr,
    const int* __restrict__ col, float* __restrict__ OUT) {
    int node = (int)((blockIdx.x * 256 + threadIdx.x) >> 5);
    int l = threadIdx.x & 31;
    if (node >= NODES) return;
    int s = row_ptr[node];
    int e = row_ptr[node + 1];
    float inv = 1.0f / (float)max(e - s, 1);
    float ax = 0.f, ay = 0.f;
    int p = s;
    for (; p + 3 < e; p += 4) {
        int c0 = col[p], c1 = col[p + 1], c2 = col[p + 2], c3 = col[p + 3];
        unsigned int u0 = T32[(size_t)c0 * 32 + l];
        unsigned int u1 = T32[(size_t)c1 * 32 + l];
        unsigned int u2 = T32[(size_t)c2 * 32 + l];
        unsigned int u3 = T32[(size_t)c3 * 32 + l];
        float2 v0 = unpackbf2(u0), v1 = unpackbf2(u1);
        float2 v2 = unpackbf2(u2), v3 = unpackbf2(u3);
        ax += (v0.x + v1.x) + (v2.x + v3.x);
        ay += (v0.y + v1.y) + (v2.y + v3.y);
    }
    for (; p < e; ++p) {
        float2 v = unpackbf2(T32[(size_t)col[p] * 32 + l]);
        ax += v.x;
        ay += v.y;
    }
    float2 o = *(float2*)(OUT + (size_t)node * 64 + l * 2);
    o.x += ax * inv;
    o.y += ay * inv;
    *(float2*)(OUT + (size_t)node * 64 + l * 2) = o;
}

// ---------------------------------------------------------------- launch

extern "C" void kernel_launch(void* const* d_in, const int* in_sizes, int n_in,
                              void* d_out, int out_size, void* d_ws, size_t ws_size,
                              hipStream_t stream) {
    const float* x   = (const float*)d_in[0];
    const float* W1l = (const float*)d_in[1];
    const float* b1  = (const float*)d_in[2];
    const float* W1r = (const float*)d_in[3];
    const float* W2l = (const float*)d_in[4];
    const float* b2  = (const float*)d_in[5];
    const float* W2r = (const float*)d_in[6];
    const int*   ei  = (const int*)d_in[7];
    const int* esrc = ei;          // edge_index[0]
    const int* edst = ei + NEDGE;  // edge_index[1]
    float* out = (float*)d_out;

    // ws layout — ~58.0 MB (within R2's proven 58.4 MB envelope).
    char* ws = (char*)d_ws;
    size_t off = 0;
    int* row_ptr  = (int*)(ws + off); off += (((size_t)(NODES + 1) * 4) + 255) & ~(size_t)255;
    int* col      = (int*)(ws + off); off += (size_t)NEDGE * 4;
    int* partials = (int*)(ws + off); off += 512;
    int* blockoff = (int*)(ws + off); off += 512;
    unsigned int* U32 = (unsigned int*)(ws + off); off += (size_t)NODES * 128 * 2;
    unsigned int* V32 = (unsigned int*)(ws + off); off += (size_t)NODES * 128 * 2;
    int* cursor = (int*)U32;          // deg/cursor alias U (dead until gemm1)
    unsigned int* T32 = U32;          // T aliases U (U dead after agg1)

    // ---- CSR build (parallel scan)
    zero_int_kernel<<<256, 256, 0, stream>>>(cursor, NODES);
    count_deg_kernel<<<2048, 256, 0, stream>>>(edst, cursor);
    scan_partial_kernel<<<SBLOCKS, 256, 0, stream>>>(cursor, partials);
    scan_offsets_kernel<<<1, 128, 0, stream>>>(partials, blockoff, row_ptr);
    scan_scatter_kernel<<<SBLOCKS, 256, 0, stream>>>(cursor, blockoff, row_ptr, cursor);
    build_csr_kernel<<<2048, 256, 0, stream>>>(esrc, edst, cursor, col);

    const int gemm_grid = (NODES + 63) / 64;  // 1563

    // ---- layer 1
    gemm1_dual_kernel<<<gemm_grid, 256, 0, stream>>>(x, W1l, W1r, b1, U32, V32);
    agg1_kernel<<<(NODES + 3) / 4, 256, 0, stream>>>(U32, row_ptr, col, V32);

    // ---- layer 2 (H = V32 in place)
    gemm2_dual_kernel<<<gemm_grid, 256, 0, stream>>>(V32, W2l, W2r, b2, T32, out);
    agg2_kernel<<<(NODES + 7) / 8, 256, 0, stream>>>(T32, row_ptr, col, out);
}

// Round 5
// 522.250 us; speedup vs baseline: 2.6752x; 1.1114x over previous
//
#include <hip/hip_runtime.h>

#define NODES 100000
#define NEDGE 1600000
#define SCHUNK 1024
#define SBLOCKS ((NODES + SCHUNK - 1) / SCHUNK)  // 98
#define NPART 8
#define PSIZE (NODES / NPART)  // 12500

// ------------------------------------------------------------ bf16 helpers

static __device__ __forceinline__ unsigned short f2bf(float x) {
    union { float f; unsigned int u; } v; v.f = x;
    unsigned int r = (v.u + 0x7fffu + ((v.u >> 16) & 1u)) >> 16;  // RNE
    return (unsigned short)r;
}
static __device__ __forceinline__ unsigned int packbf2(float a, float b) {
    return (unsigned int)f2bf(a) | ((unsigned int)f2bf(b) << 16);
}
static __device__ __forceinline__ float2 unpackbf2(unsigned int u) {
    union { unsigned int u; float f; } a, b;
    a.u = u << 16; b.u = u & 0xffff0000u;
    return make_float2(a.f, b.f);
}

// ---------------------------------------------------------------- CSR build

static __global__ void zero_int_kernel(int* __restrict__ p, int n) {
    int i = blockIdx.x * blockDim.x + threadIdx.x;
    int stride = gridDim.x * blockDim.x;
    for (; i < n; i += stride) p[i] = 0;
}

static __global__ void count_deg_kernel(const int* __restrict__ dst, int* __restrict__ deg) {
    int i = blockIdx.x * blockDim.x + threadIdx.x;
    int stride = gridDim.x * blockDim.x;
    for (int e = i; e < NEDGE; e += stride)
        atomicAdd(&deg[dst[e]], 1);
}

// Phase A: per-chunk sums.  98 blocks x 256 threads, 4 elems/thread.
static __global__ __launch_bounds__(256) void scan_partial_kernel(
    const int* __restrict__ deg, int* __restrict__ partials) {
    __shared__ int ss[256];
    int t = threadIdx.x;
    int base = blockIdx.x * SCHUNK + t * 4;
    int s = 0;
#pragma unroll
    for (int j = 0; j < 4; ++j) {
        int i = base + j;
        if (i < NODES) s += deg[i];
    }
    ss[t] = s;
    __syncthreads();
    for (int off = 128; off > 0; off >>= 1) {
        if (t < off) ss[t] += ss[t + off];
        __syncthreads();
    }
    if (t == 0) partials[blockIdx.x] = ss[0];
}

// Phase B: scan the 98 partials; also writes row_ptr[NODES].
static __global__ __launch_bounds__(128) void scan_offsets_kernel(
    const int* __restrict__ partials, int* __restrict__ block_off,
    int* __restrict__ row_ptr) {
    __shared__ int ss[128];
    int t = threadIdx.x;
    int v = (t < SBLOCKS) ? partials[t] : 0;
    ss[t] = v;
    __syncthreads();
    for (int off = 1; off < 128; off <<= 1) {
        int u = (t >= off) ? ss[t - off] : 0;
        __syncthreads();
        ss[t] += u;
        __syncthreads();
    }
    if (t < SBLOCKS) block_off[t] = ss[t] - v;  // exclusive
    if (t == 127) row_ptr[NODES] = ss[127];     // total (= NEDGE)
}

// Phase C: per-chunk exclusive scan + global offset -> row_ptr, cursor.
static __global__ __launch_bounds__(256) void scan_scatter_kernel(
    const int* deg, const int* __restrict__ block_off,
    int* __restrict__ row_ptr, int* cursor) {
    __shared__ int ss[256];
    int t = threadIdx.x;
    int base = blockIdx.x * SCHUNK + t * 4;
    int d[4];
    int s = 0;
#pragma unroll
    for (int j = 0; j < 4; ++j) {
        int i = base + j;
        d[j] = (i < NODES) ? deg[i] : 0;
        s += d[j];
    }
    ss[t] = s;
    __syncthreads();
    for (int off = 1; off < 256; off <<= 1) {
        int u = (t >= off) ? ss[t - off] : 0;
        __syncthreads();
        ss[t] += u;
        __syncthreads();
    }
    int run = block_off[blockIdx.x] + ss[t] - s;
#pragma unroll
    for (int j = 0; j < 4; ++j) {
        int i = base + j;
        if (i < NODES) {
            row_ptr[i] = run;
            cursor[i] = run;
            run += d[j];
        }
    }
}

// XCD-partitioned CSR fill.  blockIdx%8 ~ XCD id (dispatch round-robin);
// each partition handles one contiguous dst-range so its col-slice
// (~0.8 MB) stays resident in that XCD's L2 -> full-line writebacks.
// Each partition's block-group strides the whole edge list (reads are
// sequential and L3-absorbed; correctness independent of the mapping).
static __global__ __launch_bounds__(256) void build_csr_part_kernel(
    const int* __restrict__ src, const int* __restrict__ dst,
    int* __restrict__ cursor, int* __restrict__ col) {
    const int part = blockIdx.x & (NPART - 1);
    const int lo = part * PSIZE;
    const int hi = (part == NPART - 1) ? NODES : lo + PSIZE;
    const int group = blockIdx.x >> 3;
    const int ngroups = gridDim.x >> 3;
    int i = group * 256 + threadIdx.x;
    int stride = ngroups * 256;
    for (int e = i; e < NEDGE; e += stride) {
        int d = dst[e];
        if (d >= lo && d < hi) {
            int pos = atomicAdd(&cursor[d], 1);
            col[pos] = src[e];
        }
    }
}

// -------------------------------------------------- layer-1 dual GEMM
// U = bf16(X @ W1l), V = bf16(X @ W1r + b1).  X fp32 [N,128].

static __global__ __launch_bounds__(256) void gemm1_dual_kernel(
    const float* __restrict__ X, const float* __restrict__ Wl,
    const float* __restrict__ Wr, const float* __restrict__ b1,
    unsigned int* __restrict__ U32, unsigned int* __restrict__ V32) {
    __shared__ float sX[128][65];  // k-major
    const int tid = threadIdx.x;
    const int row0 = blockIdx.x * 64;

    {
        int c4 = (tid & 31) * 4;
        int r0 = tid >> 5;
#pragma unroll
        for (int p = 0; p < 8; ++p) {
            int r = r0 + p * 8;
            int row = row0 + r;
            float4 v4 = make_float4(0.f, 0.f, 0.f, 0.f);
            if (row < NODES) v4 = *(const float4*)(X + (size_t)row * 128 + c4);
            sX[c4 + 0][r] = v4.x;
            sX[c4 + 1][r] = v4.y;
            sX[c4 + 2][r] = v4.z;
            sX[c4 + 3][r] = v4.w;
        }
    }
    __syncthreads();

    const int tx = tid & 31;
    const int ty = tid >> 5;
    const int jc = tx * 4;
    const int n0 = ty * 8;

    float accU[8][4], accV[8][4];
#pragma unroll
    for (int n = 0; n < 8; ++n)
#pragma unroll
        for (int j = 0; j < 4; ++j) { accU[n][j] = 0.f; accV[n][j] = 0.f; }

    for (int k = 0; k < 128; ++k) {
        float4 wl = *(const float4*)(Wl + k * 128 + jc);
        float4 wr = *(const float4*)(Wr + k * 128 + jc);
        float a[8];
#pragma unroll
        for (int n = 0; n < 8; ++n) a[n] = sX[k][n0 + n];
#pragma unroll
        for (int n = 0; n < 8; ++n) {
            accU[n][0] += a[n] * wl.x;
            accU[n][1] += a[n] * wl.y;
            accU[n][2] += a[n] * wl.z;
            accU[n][3] += a[n] * wl.w;
            accV[n][0] += a[n] * wr.x;
            accV[n][1] += a[n] * wr.y;
            accV[n][2] += a[n] * wr.z;
            accV[n][3] += a[n] * wr.w;
        }
    }

    float4 b = *(const float4*)(b1 + jc);
#pragma unroll
    for (int n = 0; n < 8; ++n) {
        int row = row0 + n0 + n;
        if (row < NODES) {
            uint2 uu, vv;
            uu.x = packbf2(accU[n][0], accU[n][1]);
            uu.y = packbf2(accU[n][2], accU[n][3]);
            vv.x = packbf2(accV[n][0] + b.x, accV[n][1] + b.y);
            vv.y = packbf2(accV[n][2] + b.z, accV[n][3] + b.w);
            *(uint2*)&U32[(size_t)row * 64 + tx * 2] = uu;
            *(uint2*)&V32[(size_t)row * 64 + tx * 2] = vv;
        }
    }
}

// -------------------------------------------------- layer-1 aggregate

static __global__ __launch_bounds__(256) void agg1_kernel(
    const unsigned int* __restrict__ U32, const int* __restrict__ row_ptr,
    const int* __restrict__ col, unsigned int* __restrict__ H32) {
    int node = (int)((blockIdx.x * 256 + threadIdx.x) >> 6);
    int lane = threadIdx.x & 63;
    if (node >= NODES) return;
    int s = row_ptr[node];
    int e = row_ptr[node + 1];
    float inv = 1.0f / (float)max(e - s, 1);
    float ax = 0.f, ay = 0.f;
    int p = s;
    for (; p + 3 < e; p += 4) {
        int c0 = col[p], c1 = col[p + 1], c2 = col[p + 2], c3 = col[p + 3];
        unsigned int u0 = U32[(size_t)c0 * 64 + lane];
        unsigned int u1 = U32[(size_t)c1 * 64 + lane];
        unsigned int u2 = U32[(size_t)c2 * 64 + lane];
        unsigned int u3 = U32[(size_t)c3 * 64 + lane];
        float2 v0 = unpackbf2(u0), v1 = unpackbf2(u1);
        float2 v2 = unpackbf2(u2), v3 = unpackbf2(u3);
        ax += (v0.x + v1.x) + (v2.x + v3.x);
        ay += (v0.y + v1.y) + (v2.y + v3.y);
    }
    for (; p < e; ++p) {
        float2 v = unpackbf2(U32[(size_t)col[p] * 64 + lane]);
        ax += v.x;
        ay += v.y;
    }
    float2 vv = unpackbf2(H32[(size_t)node * 64 + lane]);
    float ox = fmaxf(ax * inv + vv.x, 0.f);
    float oy = fmaxf(ay * inv + vv.y, 0.f);
    H32[(size_t)node * 64 + lane] = packbf2(ox, oy);
}

// -------------------------------------------------- layer-2 dual GEMM

static __global__ __launch_bounds__(256) void gemm2_dual_kernel(
    const unsigned int* __restrict__ H32, const float* __restrict__ W2l,
    const float* __restrict__ W2r, const float* __restrict__ b2,
    unsigned int* __restrict__ T32, float* __restrict__ OUT) {
    __shared__ unsigned int sH[64][65];
    const int tid = threadIdx.x;
    const int row0 = blockIdx.x * 64;

#pragma unroll
    for (int p = 0; p < 4; ++p) {
        int gi = tid + p * 256;
        int r = gi >> 4;
        int c4 = (gi & 15) * 4;
        int row = row0 + r;
        uint4 v = make_uint4(0u, 0u, 0u, 0u);
        if (row < NODES) v = *(const uint4*)&H32[(size_t)row * 64 + c4];
        sH[r][c4 + 0] = v.x;
        sH[r][c4 + 1] = v.y;
        sH[r][c4 + 2] = v.z;
        sH[r][c4 + 3] = v.w;
    }
    __syncthreads();

    const int tx = tid & 15;
    const int ty = tid >> 4;
    const int jc = tx * 4;
    const int n0 = ty * 4;

    float accU[4][4], accV[4][4];
#pragma unroll
    for (int n = 0; n < 4; ++n)
#pragma unroll
        for (int j = 0; j < 4; ++j) { accU[n][j] = 0.f; accV[n][j] = 0.f; }

    for (int k2 = 0; k2 < 64; ++k2) {
        float4 wl0 = *(const float4*)(W2l + (2 * k2 + 0) * 64 + jc);
        float4 wl1 = *(const float4*)(W2l + (2 * k2 + 1) * 64 + jc);
        float4 wr0 = *(const float4*)(W2r + (2 * k2 + 0) * 64 + jc);
        float4 wr1 = *(const float4*)(W2r + (2 * k2 + 1) * 64 + jc);
#pragma unroll
        for (int n = 0; n < 4; ++n) {
            float2 a = unpackbf2(sH[n0 + n][k2]);
            accU[n][0] += a.x * wl0.x + a.y * wl1.x;
            accU[n][1] += a.x * wl0.y + a.y * wl1.y;
            accU[n][2] += a.x * wl0.z + a.y * wl1.z;
            accU[n][3] += a.x * wl0.w + a.y * wl1.w;
            accV[n][0] += a.x * wr0.x + a.y * wr1.x;
            accV[n][1] += a.x * wr0.y + a.y * wr1.y;
            accV[n][2] += a.x * wr0.z + a.y * wr1.z;
            accV[n][3] += a.x * wr0.w + a.y * wr1.w;
        }
    }

    float4 b = *(const float4*)(b2 + jc);
#pragma unroll
    for (int n = 0; n < 4; ++n) {
        int row = row0 + n0 + n;
        if (row < NODES) {
            uint2 t;
            t.x = packbf2(accU[n][0], accU[n][1]);
            t.y = packbf2(accU[n][2], accU[n][3]);
            *(uint2*)&T32[(size_t)row * 32 + tx * 2] = t;
            float4 r = make_float4(accV[n][0] + b.x, accV[n][1] + b.y,
                                   accV[n][2] + b.z, accV[n][3] + b.w);
            *(float4*)(OUT + (size_t)row * 64 + jc) = r;
        }
    }
}

// -------------------------------------------------- layer-2 aggregate

static __global__ __launch_bounds__(256) void agg2_kernel(
    const unsigned int* __restrict__ T32, const int* __restrict__ row_ptr,
    const int* __restrict__ col, float* __restrict__ OUT) {
    int node = (int)((blockIdx.x * 256 + threadIdx.x) >> 5);
    int l = threadIdx.x & 31;
    if (node >= NODES) return;
    int s = row_ptr[node];
    int e = row_ptr[node + 1];
    float inv = 1.0f / (float)max(e - s, 1);
    float ax = 0.f, ay = 0.f;
    int p = s;
    for (; p + 3 < e; p += 4) {
        int c0 = col[p], c1 = col[p + 1], c2 = col[p + 2], c3 = col[p + 3];
        unsigned int u0 = T32[(size_t)c0 * 32 + l];
        unsigned int u1 = T32[(size_t)c1 * 32 + l];
        unsigned int u2 = T32[(size_t)c2 * 32 + l];
        unsigned int u3 = T32[(size_t)c3 * 32 + l];
        float2 v0 = unpackbf2(u0), v1 = unpackbf2(u1);
        float2 v2 = unpackbf2(u2), v3 = unpackbf2(u3);
        ax += (v0.x + v1.x) + (v2.x + v3.x);
        ay += (v0.y + v1.y) + (v2.y + v3.y);
    }
    for (; p < e; ++p) {
        float2 v = unpackbf2(T32[(size_t)col[p] * 32 + l]);
        ax += v.x;
        ay += v.y;
    }
    float2 o = *(float2*)(OUT + (size_t)node * 64 + l * 2);
    o.x += ax * inv;
    o.y += ay * inv;
    *(float2*)(OUT + (size_t)node * 64 + l * 2) = o;
}

// ---------------------------------------------------------------- launch

extern "C" void kernel_launch(void* const* d_in, const int* in_sizes, int n_in,
                              void* d_out, int out_size, void* d_ws, size_t ws_size,
                              hipStream_t stream) {
    const float* x   = (const float*)d_in[0];
    const float* W1l = (const float*)d_in[1];
    const float* b1  = (const float*)d_in[2];
    const float* W1r = (const float*)d_in[3];
    const float* W2l = (const float*)d_in[4];
    const float* b2  = (const float*)d_in[5];
    const float* W2r = (const float*)d_in[6];
    const int*   ei  = (const int*)d_in[7];
    const int* esrc = ei;          // edge_index[0]
    const int* edst = ei + NEDGE;  // edge_index[1]
    float* out = (float*)d_out;

    // ws layout — ~58.0 MB (within R2's proven 58.4 MB envelope).
    char* ws = (char*)d_ws;
    size_t off = 0;
    int* row_ptr  = (int*)(ws + off); off += (((size_t)(NODES + 1) * 4) + 255) & ~(size_t)255;
    int* col      = (int*)(ws + off); off += (size_t)NEDGE * 4;
    int* partials = (int*)(ws + off); off += 512;
    int* blockoff = (int*)(ws + off); off += 512;
    unsigned int* U32 = (unsigned int*)(ws + off); off += (size_t)NODES * 128 * 2;
    unsigned int* V32 = (unsigned int*)(ws + off); off += (size_t)NODES * 128 * 2;
    int* cursor = (int*)U32;          // deg/cursor alias U (dead until gemm1)
    unsigned int* T32 = U32;          // T aliases U (U dead after agg1)

    // ---- CSR build (parallel scan + XCD-partitioned fill)
    zero_int_kernel<<<256, 256, 0, stream>>>(cursor, NODES);
    count_deg_kernel<<<2048, 256, 0, stream>>>(edst, cursor);
    scan_partial_kernel<<<SBLOCKS, 256, 0, stream>>>(cursor, partials);
    scan_offsets_kernel<<<1, 128, 0, stream>>>(partials, blockoff, row_ptr);
    scan_scatter_kernel<<<SBLOCKS, 256, 0, stream>>>(cursor, blockoff, row_ptr, cursor);
    build_csr_part_kernel<<<2048, 256, 0, stream>>>(esrc, edst, cursor, col);

    const int gemm_grid = (NODES + 63) / 64;  // 1563

    // ---- layer 1
    gemm1_dual_kernel<<<gemm_grid, 256, 0, stream>>>(x, W1l, W1r, b1, U32, V32);
    agg1_kernel<<<(NODES + 3) / 4, 256, 0, stream>>>(U32, row_ptr, col, V32);

    // ---- layer 2 (H = V32 in place)
    gemm2_dual_kernel<<<gemm_grid, 256, 0, stream>>>(V32, W2l, W2r, b2, T32, out);
    agg2_kernel<<<(NODES + 7) / 8, 256, 0, stream>>>(T32, row_ptr, col, out);
}

// Round 6
// 453.832 us; speedup vs baseline: 3.0785x; 1.1508x over previous
//
#include <hip/hip_runtime.h>

#define NODES 100000
#define NEDGE 1600000
#define SCHUNK 1024
#define SBLOCKS ((NODES + SCHUNK - 1) / SCHUNK)  // 98
#define NPART 8
#define PSIZE (NODES / NPART)  // 12500

typedef _Float16 half8 __attribute__((ext_vector_type(8)));
typedef float floatx4 __attribute__((ext_vector_type(4)));

// ------------------------------------------------------------ fp16 helpers

static __device__ __forceinline__ unsigned int packh2(float a, float b) {
    union { _Float16 h; unsigned short s; } x, y;
    x.h = (_Float16)a; y.h = (_Float16)b;
    return (unsigned int)x.s | ((unsigned int)y.s << 16);
}
static __device__ __forceinline__ float2 unpackh2(unsigned int u) {
    union { unsigned short s; _Float16 h; } x, y;
    x.s = (unsigned short)(u & 0xffffu);
    y.s = (unsigned short)(u >> 16);
    return make_float2((float)x.h, (float)y.h);
}

// ------------------------------------------- weight convert (fp32 -> fp16^T)
// WT1[n][k] (n<128: W1l[k][n], else W1r[k][n-128]);  WT2[n][k] similarly.

static __global__ __launch_bounds__(256) void wconv_kernel(
    const float* __restrict__ W1l, const float* __restrict__ W1r,
    const float* __restrict__ W2l, const float* __restrict__ W2r,
    _Float16* __restrict__ WT1, _Float16* __restrict__ WT2) {
    int idx = blockIdx.x * 256 + threadIdx.x;
    if (idx < 256 * 128) {
        int n = idx >> 7, k = idx & 127;
        float v = (n < 128) ? W1l[k * 128 + n] : W1r[k * 128 + (n - 128)];
        WT1[n * 128 + k] = (_Float16)v;
    } else if (idx < 256 * 128 + 128 * 128) {
        int i2 = idx - 256 * 128;
        int n = i2 >> 7, k = i2 & 127;
        float v = (n < 64) ? W2l[k * 64 + n] : W2r[k * 64 + (n - 64)];
        WT2[n * 128 + k] = (_Float16)v;
    }
}

// ---------------------------------------------------------------- CSR build

static __global__ void zero_int_kernel(int* __restrict__ p, int n) {
    int i = blockIdx.x * blockDim.x + threadIdx.x;
    int stride = gridDim.x * blockDim.x;
    for (; i < n; i += stride) p[i] = 0;
}

static __global__ void count_deg_kernel(const int* __restrict__ dst, int* __restrict__ deg) {
    int i = blockIdx.x * blockDim.x + threadIdx.x;
    int stride = gridDim.x * blockDim.x;
    for (int e = i; e < NEDGE; e += stride)
        atomicAdd(&deg[dst[e]], 1);
}

static __global__ __launch_bounds__(256) void scan_partial_kernel(
    const int* __restrict__ deg, int* __restrict__ partials) {
    __shared__ int ss[256];
    int t = threadIdx.x;
    int base = blockIdx.x * SCHUNK + t * 4;
    int s = 0;
#pragma unroll
    for (int j = 0; j < 4; ++j) {
        int i = base + j;
        if (i < NODES) s += deg[i];
    }
    ss[t] = s;
    __syncthreads();
    for (int off = 128; off > 0; off >>= 1) {
        if (t < off) ss[t] += ss[t + off];
        __syncthreads();
    }
    if (t == 0) partials[blockIdx.x] = ss[0];
}

static __global__ __launch_bounds__(128) void scan_offsets_kernel(
    const int* __restrict__ partials, int* __restrict__ block_off,
    int* __restrict__ row_ptr) {
    __shared__ int ss[128];
    int t = threadIdx.x;
    int v = (t < SBLOCKS) ? partials[t] : 0;
    ss[t] = v;
    __syncthreads();
    for (int off = 1; off < 128; off <<= 1) {
        int u = (t >= off) ? ss[t - off] : 0;
        __syncthreads();
        ss[t] += u;
        __syncthreads();
    }
    if (t < SBLOCKS) block_off[t] = ss[t] - v;  // exclusive
    if (t == 127) row_ptr[NODES] = ss[127];
}

static __global__ __launch_bounds__(256) void scan_scatter_kernel(
    const int* deg, const int* __restrict__ block_off,
    int* __restrict__ row_ptr, int* cursor) {
    __shared__ int ss[256];
    int t = threadIdx.x;
    int base = blockIdx.x * SCHUNK + t * 4;
    int d[4];
    int s = 0;
#pragma unroll
    for (int j = 0; j < 4; ++j) {
        int i = base + j;
        d[j] = (i < NODES) ? deg[i] : 0;
        s += d[j];
    }
    ss[t] = s;
    __syncthreads();
    for (int off = 1; off < 256; off <<= 1) {
        int u = (t >= off) ? ss[t - off] : 0;
        __syncthreads();
        ss[t] += u;
        __syncthreads();
    }
    int run = block_off[blockIdx.x] + ss[t] - s;
#pragma unroll
    for (int j = 0; j < 4; ++j) {
        int i = base + j;
        if (i < NODES) {
            row_ptr[i] = run;
            cursor[i] = run;
            run += d[j];
        }
    }
}

// XCD-partitioned CSR fill (R5 win: write-locality, 107->~10 MB WRITE_SIZE).
static __global__ __launch_bounds__(256) void build_csr_part_kernel(
    const int* __restrict__ src, const int* __restrict__ dst,
    int* __restrict__ cursor, int* __restrict__ col) {
    const int part = blockIdx.x & (NPART - 1);
    const int lo = part * PSIZE;
    const int hi = (part == NPART - 1) ? NODES : lo + PSIZE;
    const int group = blockIdx.x >> 3;
    const int ngroups = gridDim.x >> 3;
    int i = group * 256 + threadIdx.x;
    int stride = ngroups * 256;
    for (int e = i; e < NEDGE; e += stride) {
        int d = dst[e];
        if (d >= lo && d < hi) {
            int pos = atomicAdd(&cursor[d], 1);
            col[pos] = src[e];
        }
    }
}

// -------------------------------------------------- layer-1 MFMA dual GEMM
// U16 = fp16(X @ W1l), V16 = fp16(X @ W1r + b1).  X fp32 [N,128].
// 4 waves/block; wave w owns n-cols [64w, 64w+64): waves 0-1 -> U, 2-3 -> V.
// A-frag: A[m=lane&15][k=quad*8+j] from LDS; B-frag: WT1[n=lane&15-slice][k]
// from global (L1/L2-resident, 64 KB).  C/D: col=lane&15, row=quad*4+reg.

static __global__ __launch_bounds__(256) void gemm1_mfma_kernel(
    const float* __restrict__ X, const _Float16* __restrict__ WT1,
    const float* __restrict__ b1,
    _Float16* __restrict__ U16, _Float16* __restrict__ V16) {
    __shared__ _Float16 sX[64][136];  // pad 136: A-frag rows spread over banks
    const int tid = threadIdx.x;
    const int row0 = blockIdx.x * 64;
    {
        int c4 = (tid & 31) * 4;
        int r0 = tid >> 5;
#pragma unroll
        for (int p = 0; p < 8; ++p) {
            int r = r0 + p * 8;
            int row = row0 + r;
            float4 v = make_float4(0.f, 0.f, 0.f, 0.f);
            if (row < NODES) v = *(const float4*)(X + (size_t)row * 128 + c4);
            sX[r][c4 + 0] = (_Float16)v.x;
            sX[r][c4 + 1] = (_Float16)v.y;
            sX[r][c4 + 2] = (_Float16)v.z;
            sX[r][c4 + 3] = (_Float16)v.w;
        }
    }
    __syncthreads();

    const int wave = tid >> 6;
    const int lane = tid & 63;
    const int l15 = lane & 15;
    const int quad = lane >> 4;

    floatx4 acc[4][4];  // [j][m]
#pragma unroll
    for (int j = 0; j < 4; ++j)
#pragma unroll
        for (int m = 0; m < 4; ++m) acc[j][m] = (floatx4){0.f, 0.f, 0.f, 0.f};

    const _Float16* Wbase = WT1 + (size_t)(wave * 64 + l15) * 128 + quad * 8;

    for (int k0 = 0; k0 < 128; k0 += 32) {
        half8 a[4];
#pragma unroll
        for (int m = 0; m < 4; ++m)
            a[m] = *(const half8*)&sX[m * 16 + l15][quad * 8 + k0];
#pragma unroll
        for (int j = 0; j < 4; ++j) {
            half8 b = *(const half8*)(Wbase + (size_t)j * 16 * 128 + k0);
#pragma unroll
            for (int m = 0; m < 4; ++m)
                acc[j][m] = __builtin_amdgcn_mfma_f32_16x16x32_f16(a[m], b, acc[j][m], 0, 0, 0);
        }
    }

    const int nbase = wave * 64 + l15;
#pragma unroll
    for (int j = 0; j < 4; ++j) {
        int n = nbase + j * 16;
        bool isV = (n >= 128);          // wave-uniform
        int nn = isV ? n - 128 : n;
        float badd = isV ? b1[nn] : 0.f;
        _Float16* Dst = isV ? V16 : U16;
#pragma unroll
        for (int m = 0; m < 4; ++m)
#pragma unroll
            for (int r = 0; r < 4; ++r) {
                int row = row0 + m * 16 + quad * 4 + r;
                if (row < NODES)
                    Dst[(size_t)row * 128 + nn] = (_Float16)(acc[j][m][r] + badd);
            }
    }
}

// -------------------------------------------------- layer-1 aggregate
// H[i] = fp16(relu(mean_j U[j] + V[i])), in place over V (fp16 tables).

static __global__ __launch_bounds__(256) void agg1_kernel(
    const unsigned int* __restrict__ U32, const int* __restrict__ row_ptr,
    const int* __restrict__ col, unsigned int* __restrict__ H32) {
    int node = (int)((blockIdx.x * 256 + threadIdx.x) >> 6);
    int lane = threadIdx.x & 63;
    if (node >= NODES) return;
    int s = row_ptr[node];
    int e = row_ptr[node + 1];
    float inv = 1.0f / (float)max(e - s, 1);
    float ax = 0.f, ay = 0.f;
    int p = s;
    for (; p + 3 < e; p += 4) {
        int c0 = col[p], c1 = col[p + 1], c2 = col[p + 2], c3 = col[p + 3];
        unsigned int u0 = U32[(size_t)c0 * 64 + lane];
        unsigned int u1 = U32[(size_t)c1 * 64 + lane];
        unsigned int u2 = U32[(size_t)c2 * 64 + lane];
        unsigned int u3 = U32[(size_t)c3 * 64 + lane];
        float2 v0 = unpackh2(u0), v1 = unpackh2(u1);
        float2 v2 = unpackh2(u2), v3 = unpackh2(u3);
        ax += (v0.x + v1.x) + (v2.x + v3.x);
        ay += (v0.y + v1.y) + (v2.y + v3.y);
    }
    for (; p < e; ++p) {
        float2 v = unpackh2(U32[(size_t)col[p] * 64 + lane]);
        ax += v.x;
        ay += v.y;
    }
    float2 vv = unpackh2(H32[(size_t)node * 64 + lane]);
    float ox = fmaxf(ax * inv + vv.x, 0.f);
    float oy = fmaxf(ay * inv + vv.y, 0.f);
    H32[(size_t)node * 64 + lane] = packh2(ox, oy);
}

// -------------------------------------------------- layer-2 MFMA dual GEMM
// T16 = fp16(H @ W2l)  (waves 0-1),  OUT = H @ W2r + b2 fp32 (waves 2-3).

static __global__ __launch_bounds__(256) void gemm2_mfma_kernel(
    const _Float16* __restrict__ H16, const _Float16* __restrict__ WT2,
    const float* __restrict__ b2,
    _Float16* __restrict__ T16, float* __restrict__ OUT) {
    __shared__ _Float16 sX[64][136];
    const int tid = threadIdx.x;
    const int row0 = blockIdx.x * 64;
    {
        int c8 = (tid & 15) * 8;
        int r0 = tid >> 4;
#pragma unroll
        for (int p = 0; p < 4; ++p) {
            int r = r0 + p * 16;
            int row = row0 + r;
            uint4 v = make_uint4(0u, 0u, 0u, 0u);
            if (row < NODES) v = *(const uint4*)(H16 + (size_t)row * 128 + c8);
            *(uint4*)&sX[r][c8] = v;
        }
    }
    __syncthreads();

    const int wave = tid >> 6;
    const int lane = tid & 63;
    const int l15 = lane & 15;
    const int quad = lane >> 4;

    floatx4 acc[2][4];  // [j][m]
#pragma unroll
    for (int j = 0; j < 2; ++j)
#pragma unroll
        for (int m = 0; m < 4; ++m) acc[j][m] = (floatx4){0.f, 0.f, 0.f, 0.f};

    const _Float16* Wbase = WT2 + (size_t)(wave * 32 + l15) * 128 + quad * 8;

    for (int k0 = 0; k0 < 128; k0 += 32) {
        half8 a[4];
#pragma unroll
        for (int m = 0; m < 4; ++m)
            a[m] = *(const half8*)&sX[m * 16 + l15][quad * 8 + k0];
#pragma unroll
        for (int j = 0; j < 2; ++j) {
            half8 b = *(const half8*)(Wbase + (size_t)j * 16 * 128 + k0);
#pragma unroll
            for (int m = 0; m < 4; ++m)
                acc[j][m] = __builtin_amdgcn_mfma_f32_16x16x32_f16(a[m], b, acc[j][m], 0, 0, 0);
        }
    }

    const int nbase = wave * 32 + l15;
#pragma unroll
    for (int j = 0; j < 2; ++j) {
        int n = nbase + j * 16;
        bool isOut = (n >= 64);         // wave-uniform
        int nn = isOut ? n - 64 : n;
        float badd = isOut ? b2[nn] : 0.f;
#pragma unroll
        for (int m = 0; m < 4; ++m)
#pragma unroll
            for (int r = 0; r < 4; ++r) {
                int row = row0 + m * 16 + quad * 4 + r;
                if (row < NODES) {
                    float v = acc[j][m][r] + badd;
                    if (isOut) OUT[(size_t)row * 64 + nn] = v;
                    else       T16[(size_t)row * 64 + nn] = (_Float16)v;
                }
            }
    }
}

// -------------------------------------------------- layer-2 aggregate

static __global__ __launch_bounds__(256) void agg2_kernel(
    const unsigned int* __restrict__ T32, const int* __restrict__ row_ptr,
    const int* __restrict__ col, float* __restrict__ OUT) {
    int node = (int)((blockIdx.x * 256 + threadIdx.x) >> 5);
    int l = threadIdx.x & 31;
    if (node >= NODES) return;
    int s = row_ptr[node];
    int e = row_ptr[node + 1];
    float inv = 1.0f / (float)max(e - s, 1);
    float ax = 0.f, ay = 0.f;
    int p = s;
    for (; p + 3 < e; p += 4) {
        int c0 = col[p], c1 = col[p + 1], c2 = col[p + 2], c3 = col[p + 3];
        unsigned int u0 = T32[(size_t)c0 * 32 + l];
        unsigned int u1 = T32[(size_t)c1 * 32 + l];
        unsigned int u2 = T32[(size_t)c2 * 32 + l];
        unsigned int u3 = T32[(size_t)c3 * 32 + l];
        float2 v0 = unpackh2(u0), v1 = unpackh2(u1);
        float2 v2 = unpackh2(u2), v3 = unpackh2(u3);
        ax += (v0.x + v1.x) + (v2.x + v3.x);
        ay += (v0.y + v1.y) + (v2.y + v3.y);
    }
    for (; p < e; ++p) {
        float2 v = unpackh2(T32[(size_t)col[p] * 32 + l]);
        ax += v.x;
        ay += v.y;
    }
    float2 o = *(float2*)(OUT + (size_t)node * 64 + l * 2);
    o.x += ax * inv;
    o.y += ay * inv;
    *(float2*)(OUT + (size_t)node * 64 + l * 2) = o;
}

// ---------------------------------------------------------------- launch

extern "C" void kernel_launch(void* const* d_in, const int* in_sizes, int n_in,
                              void* d_out, int out_size, void* d_ws, size_t ws_size,
                              hipStream_t stream) {
    const float* x   = (const float*)d_in[0];
    const float* W1l = (const float*)d_in[1];
    const float* b1  = (const float*)d_in[2];
    const float* W1r = (const float*)d_in[3];
    const float* W2l = (const float*)d_in[4];
    const float* b2  = (const float*)d_in[5];
    const float* W2r = (const float*)d_in[6];
    const int*   ei  = (const int*)d_in[7];
    const int* esrc = ei;          // edge_index[0]
    const int* edst = ei + NEDGE;  // edge_index[1]
    float* out = (float*)d_out;

    // ws layout — ~58.1 MB (within R2's proven 58.4 MB envelope).
    char* ws = (char*)d_ws;
    size_t off = 0;
    int* row_ptr  = (int*)(ws + off); off += (((size_t)(NODES + 1) * 4) + 255) & ~(size_t)255;
    int* col      = (int*)(ws + off); off += (size_t)NEDGE * 4;
    int* partials = (int*)(ws + off); off += 512;
    int* blockoff = (int*)(ws + off); off += 512;
    _Float16* WT1 = (_Float16*)(ws + off); off += 256 * 128 * 2;
    _Float16* WT2 = (_Float16*)(ws + off); off += 128 * 128 * 2;
    _Float16* U16 = (_Float16*)(ws + off); off += (size_t)NODES * 128 * 2;
    _Float16* V16 = (_Float16*)(ws + off); off += (size_t)NODES * 128 * 2;
    int* cursor = (int*)U16;          // deg/cursor alias U (dead until gemm1)
    _Float16* T16 = U16;              // T aliases U (U dead after agg1)

    // ---- weight conversion + CSR build
    wconv_kernel<<<192, 256, 0, stream>>>(W1l, W1r, W2l, W2r, WT1, WT2);
    zero_int_kernel<<<256, 256, 0, stream>>>(cursor, NODES);
    count_deg_kernel<<<2048, 256, 0, stream>>>(edst, cursor);
    scan_partial_kernel<<<SBLOCKS, 256, 0, stream>>>(cursor, partials);
    scan_offsets_kernel<<<1, 128, 0, stream>>>(partials, blockoff, row_ptr);
    scan_scatter_kernel<<<SBLOCKS, 256, 0, stream>>>(cursor, blockoff, row_ptr, cursor);
    build_csr_part_kernel<<<2048, 256, 0, stream>>>(esrc, edst, cursor, col);

    const int gemm_grid = (NODES + 63) / 64;  // 1563

    // ---- layer 1
    gemm1_mfma_kernel<<<gemm_grid, 256, 0, stream>>>(x, WT1, b1, U16, V16);
    agg1_kernel<<<(NODES + 3) / 4, 256, 0, stream>>>(
        (const unsigned int*)U16, row_ptr, col, (unsigned int*)V16);

    // ---- layer 2 (H = V16 in place)
    gemm2_mfma_kernel<<<gemm_grid, 256, 0, stream>>>(V16, WT2, b2, T16, out);
    agg2_kernel<<<(NODES + 7) / 8, 256, 0, stream>>>(
        (const unsigned int*)T16, row_ptr, col, out);
}

// Round 7
// 444.957 us; speedup vs baseline: 3.1399x; 1.0199x over previous
//
#include <hip/hip_runtime.h>

#define NODES 100000
#define NEDGE 1600000
#define SCHUNK 1024
#define SBLOCKS ((NODES + SCHUNK - 1) / SCHUNK)  // 98
#define NPART 8
#define PSIZE (NODES / NPART)  // 12500

typedef _Float16 half8 __attribute__((ext_vector_type(8)));
typedef float floatx4 __attribute__((ext_vector_type(4)));
typedef float floatx2 __attribute__((ext_vector_type(2)));

// ------------------------------------------------------------ fp16 helpers

static __device__ __forceinline__ unsigned int packh2(float a, float b) {
    union { _Float16 h; unsigned short s; } x, y;
    x.h = (_Float16)a; y.h = (_Float16)b;
    return (unsigned int)x.s | ((unsigned int)y.s << 16);
}
static __device__ __forceinline__ float2 unpackh2(unsigned int u) {
    union { unsigned short s; _Float16 h; } x, y;
    x.s = (unsigned short)(u & 0xffffu);
    y.s = (unsigned short)(u >> 16);
    return make_float2((float)x.h, (float)y.h);
}

// ------------------------------------------------------------ fp8 helpers
// OCP e4m3 via HW cvt (gfx950).

static __device__ __forceinline__ unsigned char f2fp8(float x) {
    return (unsigned char)(__builtin_amdgcn_cvt_pk_fp8_f32(x, x, 0, false) & 0xff);
}
static __device__ __forceinline__ float2 fp8x2_to_f32(unsigned int u) {
    floatx2 r = __builtin_amdgcn_cvt_pk_f32_fp8(u, false);
    return make_float2(r.x, r.y);
}

// ------------------------------------------- weight convert (fp32 -> fp16^T)

static __global__ __launch_bounds__(256) void wconv_kernel(
    const float* __restrict__ W1l, const float* __restrict__ W1r,
    const float* __restrict__ W2l, const float* __restrict__ W2r,
    _Float16* __restrict__ WT1, _Float16* __restrict__ WT2) {
    int idx = blockIdx.x * 256 + threadIdx.x;
    if (idx < 256 * 128) {
        int n = idx >> 7, k = idx & 127;
        float v = (n < 128) ? W1l[k * 128 + n] : W1r[k * 128 + (n - 128)];
        WT1[n * 128 + k] = (_Float16)v;
    } else if (idx < 256 * 128 + 128 * 128) {
        int i2 = idx - 256 * 128;
        int n = i2 >> 7, k = i2 & 127;
        float v = (n < 64) ? W2l[k * 64 + n] : W2r[k * 64 + (n - 64)];
        WT2[n * 128 + k] = (_Float16)v;
    }
}

// ---------------------------------------------------------------- CSR build

static __global__ void zero_int_kernel(int* __restrict__ p, int n) {
    int i = blockIdx.x * blockDim.x + threadIdx.x;
    int stride = gridDim.x * blockDim.x;
    for (; i < n; i += stride) p[i] = 0;
}

static __global__ void count_deg_kernel(const int* __restrict__ dst, int* __restrict__ deg) {
    int i = blockIdx.x * blockDim.x + threadIdx.x;
    int stride = gridDim.x * blockDim.x;
    for (int e = i; e < NEDGE; e += stride)
        atomicAdd(&deg[dst[e]], 1);
}

static __global__ __launch_bounds__(256) void scan_partial_kernel(
    const int* __restrict__ deg, int* __restrict__ partials) {
    __shared__ int ss[256];
    int t = threadIdx.x;
    int base = blockIdx.x * SCHUNK + t * 4;
    int s = 0;
#pragma unroll
    for (int j = 0; j < 4; ++j) {
        int i = base + j;
        if (i < NODES) s += deg[i];
    }
    ss[t] = s;
    __syncthreads();
    for (int off = 128; off > 0; off >>= 1) {
        if (t < off) ss[t] += ss[t + off];
        __syncthreads();
    }
    if (t == 0) partials[blockIdx.x] = ss[0];
}

static __global__ __launch_bounds__(128) void scan_offsets_kernel(
    const int* __restrict__ partials, int* __restrict__ block_off,
    int* __restrict__ row_ptr) {
    __shared__ int ss[128];
    int t = threadIdx.x;
    int v = (t < SBLOCKS) ? partials[t] : 0;
    ss[t] = v;
    __syncthreads();
    for (int off = 1; off < 128; off <<= 1) {
        int u = (t >= off) ? ss[t - off] : 0;
        __syncthreads();
        ss[t] += u;
        __syncthreads();
    }
    if (t < SBLOCKS) block_off[t] = ss[t] - v;  // exclusive
    if (t == 127) row_ptr[NODES] = ss[127];
}

static __global__ __launch_bounds__(256) void scan_scatter_kernel(
    const int* deg, const int* __restrict__ block_off,
    int* __restrict__ row_ptr, int* cursor) {
    __shared__ int ss[256];
    int t = threadIdx.x;
    int base = blockIdx.x * SCHUNK + t * 4;
    int d[4];
    int s = 0;
#pragma unroll
    for (int j = 0; j < 4; ++j) {
        int i = base + j;
        d[j] = (i < NODES) ? deg[i] : 0;
        s += d[j];
    }
    ss[t] = s;
    __syncthreads();
    for (int off = 1; off < 256; off <<= 1) {
        int u = (t >= off) ? ss[t - off] : 0;
        __syncthreads();
        ss[t] += u;
        __syncthreads();
    }
    int run = block_off[blockIdx.x] + ss[t] - s;
#pragma unroll
    for (int j = 0; j < 4; ++j) {
        int i = base + j;
        if (i < NODES) {
            row_ptr[i] = run;
            cursor[i] = run;
            run += d[j];
        }
    }
}

// XCD-partitioned CSR fill (R5 win: write-locality).
static __global__ __launch_bounds__(256) void build_csr_part_kernel(
    const int* __restrict__ src, const int* __restrict__ dst,
    int* __restrict__ cursor, int* __restrict__ col) {
    const int part = blockIdx.x & (NPART - 1);
    const int lo = part * PSIZE;
    const int hi = (part == NPART - 1) ? NODES : lo + PSIZE;
    const int group = blockIdx.x >> 3;
    const int ngroups = gridDim.x >> 3;
    int i = group * 256 + threadIdx.x;
    int stride = ngroups * 256;
    for (int e = i; e < NEDGE; e += stride) {
        int d = dst[e];
        if (d >= lo && d < hi) {
            int pos = atomicAdd(&cursor[d], 1);
            col[pos] = src[e];
        }
    }
}

// -------------------------------------------------- layer-1 MFMA dual GEMM
// U8 = fp8(X @ W1l)  (waves 0-1),  V16 = fp16(X @ W1r + b1)  (waves 2-3).

static __global__ __launch_bounds__(256) void gemm1_mfma_kernel(
    const float* __restrict__ X, const _Float16* __restrict__ WT1,
    const float* __restrict__ b1,
    unsigned char* __restrict__ U8, _Float16* __restrict__ V16) {
    __shared__ _Float16 sX[64][136];
    const int tid = threadIdx.x;
    const int row0 = blockIdx.x * 64;
    {
        int c4 = (tid & 31) * 4;
        int r0 = tid >> 5;
#pragma unroll
        for (int p = 0; p < 8; ++p) {
            int r = r0 + p * 8;
            int row = row0 + r;
            float4 v = make_float4(0.f, 0.f, 0.f, 0.f);
            if (row < NODES) v = *(const float4*)(X + (size_t)row * 128 + c4);
            sX[r][c4 + 0] = (_Float16)v.x;
            sX[r][c4 + 1] = (_Float16)v.y;
            sX[r][c4 + 2] = (_Float16)v.z;
            sX[r][c4 + 3] = (_Float16)v.w;
        }
    }
    __syncthreads();

    const int wave = tid >> 6;
    const int lane = tid & 63;
    const int l15 = lane & 15;
    const int quad = lane >> 4;

    floatx4 acc[4][4];  // [j][m]
#pragma unroll
    for (int j = 0; j < 4; ++j)
#pragma unroll
        for (int m = 0; m < 4; ++m) acc[j][m] = (floatx4){0.f, 0.f, 0.f, 0.f};

    const _Float16* Wbase = WT1 + (size_t)(wave * 64 + l15) * 128 + quad * 8;

    for (int k0 = 0; k0 < 128; k0 += 32) {
        half8 a[4];
#pragma unroll
        for (int m = 0; m < 4; ++m)
            a[m] = *(const half8*)&sX[m * 16 + l15][quad * 8 + k0];
#pragma unroll
        for (int j = 0; j < 4; ++j) {
            half8 b = *(const half8*)(Wbase + (size_t)j * 16 * 128 + k0);
#pragma unroll
            for (int m = 0; m < 4; ++m)
                acc[j][m] = __builtin_amdgcn_mfma_f32_16x16x32_f16(a[m], b, acc[j][m], 0, 0, 0);
        }
    }

    const int nbase = wave * 64 + l15;
    if (wave < 2) {
        // U half: n in [0,128), fp8 output, row stride 128 B
#pragma unroll
        for (int j = 0; j < 4; ++j) {
            int n = nbase + j * 16;
#pragma unroll
            for (int m = 0; m < 4; ++m)
#pragma unroll
                for (int r = 0; r < 4; ++r) {
                    int row = row0 + m * 16 + quad * 4 + r;
                    if (row < NODES)
                        U8[(size_t)row * 128 + n] = f2fp8(acc[j][m][r]);
                }
        }
    } else {
        // V half: n-128 in [0,128), fp16 output + bias
#pragma unroll
        for (int j = 0; j < 4; ++j) {
            int nn = nbase + j * 16 - 128;
            float badd = b1[nn];
#pragma unroll
            for (int m = 0; m < 4; ++m)
#pragma unroll
                for (int r = 0; r < 4; ++r) {
                    int row = row0 + m * 16 + quad * 4 + r;
                    if (row < NODES)
                        V16[(size_t)row * 128 + nn] = (_Float16)(acc[j][m][r] + badd);
                }
        }
    }
}

// -------------------------------------------------- layer-1 aggregate
// H[i] = fp16(relu(mean_j U8[j] + V[i])), in place over V.
// One wave/node; lane reads 2 fp8 (ushort) per edge -> 128 B/row.

static __global__ __launch_bounds__(256) void agg1_kernel(
    const unsigned char* __restrict__ U8, const int* __restrict__ row_ptr,
    const int* __restrict__ col, unsigned int* __restrict__ H32) {
    int node = (int)((blockIdx.x * 256 + threadIdx.x) >> 6);
    int lane = threadIdx.x & 63;
    if (node >= NODES) return;
    int s = row_ptr[node];
    int e = row_ptr[node + 1];
    float inv = 1.0f / (float)max(e - s, 1);
    float ax = 0.f, ay = 0.f;
    int p = s;
    for (; p + 3 < e; p += 4) {
        int c0 = col[p], c1 = col[p + 1], c2 = col[p + 2], c3 = col[p + 3];
        unsigned int u0 = *(const unsigned short*)(U8 + (size_t)c0 * 128 + lane * 2);
        unsigned int u1 = *(const unsigned short*)(U8 + (size_t)c1 * 128 + lane * 2);
        unsigned int u2 = *(const unsigned short*)(U8 + (size_t)c2 * 128 + lane * 2);
        unsigned int u3 = *(const unsigned short*)(U8 + (size_t)c3 * 128 + lane * 2);
        float2 v0 = fp8x2_to_f32(u0), v1 = fp8x2_to_f32(u1);
        float2 v2 = fp8x2_to_f32(u2), v3 = fp8x2_to_f32(u3);
        ax += (v0.x + v1.x) + (v2.x + v3.x);
        ay += (v0.y + v1.y) + (v2.y + v3.y);
    }
    for (; p < e; ++p) {
        unsigned int u = *(const unsigned short*)(U8 + (size_t)col[p] * 128 + lane * 2);
        float2 v = fp8x2_to_f32(u);
        ax += v.x;
        ay += v.y;
    }
    float2 vv = unpackh2(H32[(size_t)node * 64 + lane]);
    float ox = fmaxf(ax * inv + vv.x, 0.f);
    float oy = fmaxf(ay * inv + vv.y, 0.f);
    H32[(size_t)node * 64 + lane] = packh2(ox, oy);
}

// -------------------------------------------------- layer-2 MFMA dual GEMM
// T16 = fp16(H @ W2l)  (waves 0-1),  OUT = H @ W2r + b2 fp32 (waves 2-3).

static __global__ __launch_bounds__(256) void gemm2_mfma_kernel(
    const _Float16* __restrict__ H16, const _Float16* __restrict__ WT2,
    const float* __restrict__ b2,
    _Float16* __restrict__ T16, float* __restrict__ OUT) {
    __shared__ _Float16 sX[64][136];
    const int tid = threadIdx.x;
    const int row0 = blockIdx.x * 64;
    {
        int c8 = (tid & 15) * 8;
        int r0 = tid >> 4;
#pragma unroll
        for (int p = 0; p < 4; ++p) {
            int r = r0 + p * 16;
            int row = row0 + r;
            uint4 v = make_uint4(0u, 0u, 0u, 0u);
            if (row < NODES) v = *(const uint4*)(H16 + (size_t)row * 128 + c8);
            *(uint4*)&sX[r][c8] = v;
        }
    }
    __syncthreads();

    const int wave = tid >> 6;
    const int lane = tid & 63;
    const int l15 = lane & 15;
    const int quad = lane >> 4;

    floatx4 acc[2][4];
#pragma unroll
    for (int j = 0; j < 2; ++j)
#pragma unroll
        for (int m = 0; m < 4; ++m) acc[j][m] = (floatx4){0.f, 0.f, 0.f, 0.f};

    const _Float16* Wbase = WT2 + (size_t)(wave * 32 + l15) * 128 + quad * 8;

    for (int k0 = 0; k0 < 128; k0 += 32) {
        half8 a[4];
#pragma unroll
        for (int m = 0; m < 4; ++m)
            a[m] = *(const half8*)&sX[m * 16 + l15][quad * 8 + k0];
#pragma unroll
        for (int j = 0; j < 2; ++j) {
            half8 b = *(const half8*)(Wbase + (size_t)j * 16 * 128 + k0);
#pragma unroll
            for (int m = 0; m < 4; ++m)
                acc[j][m] = __builtin_amdgcn_mfma_f32_16x16x32_f16(a[m], b, acc[j][m], 0, 0, 0);
        }
    }

    const int nbase = wave * 32 + l15;
#pragma unroll
    for (int j = 0; j < 2; ++j) {
        int n = nbase + j * 16;
        bool isOut = (n >= 64);
        int nn = isOut ? n - 64 : n;
        float badd = isOut ? b2[nn] : 0.f;
#pragma unroll
        for (int m = 0; m < 4; ++m)
#pragma unroll
            for (int r = 0; r < 4; ++r) {
                int row = row0 + m * 16 + quad * 4 + r;
                if (row < NODES) {
                    float v = acc[j][m][r] + badd;
                    if (isOut) OUT[(size_t)row * 64 + nn] = v;
                    else       T16[(size_t)row * 64 + nn] = (_Float16)v;
                }
            }
    }
}

// -------------------------------------------------- layer-2 aggregate

static __global__ __launch_bounds__(256) void agg2_kernel(
    const unsigned int* __restrict__ T32, const int* __restrict__ row_ptr,
    const int* __restrict__ col, float* __restrict__ OUT) {
    int node = (int)((blockIdx.x * 256 + threadIdx.x) >> 5);
    int l = threadIdx.x & 31;
    if (node >= NODES) return;
    int s = row_ptr[node];
    int e = row_ptr[node + 1];
    float inv = 1.0f / (float)max(e - s, 1);
    float ax = 0.f, ay = 0.f;
    int p = s;
    for (; p + 3 < e; p += 4) {
        int c0 = col[p], c1 = col[p + 1], c2 = col[p + 2], c3 = col[p + 3];
        unsigned int u0 = T32[(size_t)c0 * 32 + l];
        unsigned int u1 = T32[(size_t)c1 * 32 + l];
        unsigned int u2 = T32[(size_t)c2 * 32 + l];
        unsigned int u3 = T32[(size_t)c3 * 32 + l];
        float2 v0 = unpackh2(u0), v1 = unpackh2(u1);
        float2 v2 = unpackh2(u2), v3 = unpackh2(u3);
        ax += (v0.x + v1.x) + (v2.x + v3.x);
        ay += (v0.y + v1.y) + (v2.y + v3.y);
    }
    for (; p < e; ++p) {
        float2 v = unpackh2(T32[(size_t)col[p] * 32 + l]);
        ax += v.x;
        ay += v.y;
    }
    float2 o = *(float2*)(OUT + (size_t)node * 64 + l * 2);
    o.x += ax * inv;
    o.y += ay * inv;
    *(float2*)(OUT + (size_t)node * 64 + l * 2) = o;
}

// ---------------------------------------------------------------- launch

extern "C" void kernel_launch(void* const* d_in, const int* in_sizes, int n_in,
                              void* d_out, int out_size, void* d_ws, size_t ws_size,
                              hipStream_t stream) {
    const float* x   = (const float*)d_in[0];
    const float* W1l = (const float*)d_in[1];
    const float* b1  = (const float*)d_in[2];
    const float* W1r = (const float*)d_in[3];
    const float* W2l = (const float*)d_in[4];
    const float* b2  = (const float*)d_in[5];
    const float* W2r = (const float*)d_in[6];
    const int*   ei  = (const int*)d_in[7];
    const int* esrc = ei;          // edge_index[0]
    const int* edst = ei + NEDGE;  // edge_index[1]
    float* out = (float*)d_out;

    // ws layout — ~45.3 MB (well inside the proven 58.4 MB envelope).
    char* ws = (char*)d_ws;
    size_t off = 0;
    int* row_ptr  = (int*)(ws + off); off += (((size_t)(NODES + 1) * 4) + 255) & ~(size_t)255;
    int* col      = (int*)(ws + off); off += (size_t)NEDGE * 4;
    int* partials = (int*)(ws + off); off += 512;
    int* blockoff = (int*)(ws + off); off += 512;
    _Float16* WT1 = (_Float16*)(ws + off); off += 256 * 128 * 2;
    _Float16* WT2 = (_Float16*)(ws + off); off += 128 * 128 * 2;
    unsigned char* U8 = (unsigned char*)(ws + off); off += (size_t)NODES * 128;      // fp8 table
    _Float16* V16 = (_Float16*)(ws + off); off += (size_t)NODES * 128 * 2;           // v, then h
    int* cursor = (int*)U8;            // deg/cursor alias U8 (dead until gemm1)
    _Float16* T16 = (_Float16*)U8;     // T (12.8 MB) aliases U8 (dead after agg1)

    // ---- weight conversion + CSR build
    wconv_kernel<<<192, 256, 0, stream>>>(W1l, W1r, W2l, W2r, WT1, WT2);
    zero_int_kernel<<<256, 256, 0, stream>>>(cursor, NODES);
    count_deg_kernel<<<2048, 256, 0, stream>>>(edst, cursor);
    scan_partial_kernel<<<SBLOCKS, 256, 0, stream>>>(cursor, partials);
    scan_offsets_kernel<<<1, 128, 0, stream>>>(partials, blockoff, row_ptr);
    scan_scatter_kernel<<<SBLOCKS, 256, 0, stream>>>(cursor, blockoff, row_ptr, cursor);
    build_csr_part_kernel<<<2048, 256, 0, stream>>>(esrc, edst, cursor, col);

    const int gemm_grid = (NODES + 63) / 64;  // 1563

    // ---- layer 1
    gemm1_mfma_kernel<<<gemm_grid, 256, 0, stream>>>(x, WT1, b1, U8, V16);
    agg1_kernel<<<(NODES + 3) / 4, 256, 0, stream>>>(
        U8, row_ptr, col, (unsigned int*)V16);

    // ---- layer 2 (H = V16 in place)
    gemm2_mfma_kernel<<<gemm_grid, 256, 0, stream>>>(V16, WT2, b2, T16, out);
    agg2_kernel<<<(NODES + 7) / 8, 256, 0, stream>>>(
        (const unsigned int*)T16, row_ptr, col, out);
}

// Round 9
// 419.196 us; speedup vs baseline: 3.3329x; 1.0615x over previous
//
#include <hip/hip_runtime.h>

#define NODES 100000
#define NEDGE 1600000
#define SCHUNK 1024
#define SBLOCKS ((NODES + SCHUNK - 1) / SCHUNK)  // 98
#define NPART 8
#define PSIZE (NODES / NPART)  // 12500

typedef _Float16 half8 __attribute__((ext_vector_type(8)));
typedef float floatx4 __attribute__((ext_vector_type(4)));
typedef float floatx2 __attribute__((ext_vector_type(2)));

// ------------------------------------------------------------ fp16 helpers

static __device__ __forceinline__ unsigned int packh2(float a, float b) {
    union { _Float16 h; unsigned short s; } x, y;
    x.h = (_Float16)a; y.h = (_Float16)b;
    return (unsigned int)x.s | ((unsigned int)y.s << 16);
}
static __device__ __forceinline__ float2 unpackh2(unsigned int u) {
    union { unsigned short s; _Float16 h; } x, y;
    x.s = (unsigned short)(u & 0xffffu);
    y.s = (unsigned short)(u >> 16);
    return make_float2((float)x.h, (float)y.h);
}

// ------------------------------------------------------------ fp8 helpers
// Word-select of cvt_pk_f32_fp8 must be an immediate -> template param.

static __device__ __forceinline__ unsigned char f2fp8(float x) {
    return (unsigned char)(__builtin_amdgcn_cvt_pk_fp8_f32(x, x, 0, false) & 0xff);
}
template <bool HI>
static __device__ __forceinline__ float2 fp8x2_to_f32(unsigned int u) {
    floatx2 r = __builtin_amdgcn_cvt_pk_f32_fp8(u, HI);
    return make_float2(r.x, r.y);
}

// ------------------------------------------- weight convert (fp32 -> fp16^T)

static __global__ __launch_bounds__(256) void wconv_kernel(
    const float* __restrict__ W1l, const float* __restrict__ W1r,
    const float* __restrict__ W2l, const float* __restrict__ W2r,
    _Float16* __restrict__ WT1, _Float16* __restrict__ WT2) {
    int idx = blockIdx.x * 256 + threadIdx.x;
    if (idx < 256 * 128) {
        int n = idx >> 7, k = idx & 127;
        float v = (n < 128) ? W1l[k * 128 + n] : W1r[k * 128 + (n - 128)];
        WT1[n * 128 + k] = (_Float16)v;
    } else if (idx < 256 * 128 + 128 * 128) {
        int i2 = idx - 256 * 128;
        int n = i2 >> 7, k = i2 & 127;
        float v = (n < 64) ? W2l[k * 64 + n] : W2r[k * 64 + (n - 64)];
        WT2[n * 128 + k] = (_Float16)v;
    }
}

// ---------------------------------------------------------------- CSR build

static __global__ void zero_int_kernel(int* __restrict__ p, int n) {
    int i = blockIdx.x * blockDim.x + threadIdx.x;
    int stride = gridDim.x * blockDim.x;
    for (; i < n; i += stride) p[i] = 0;
}

// XCD-partitioned degree count (same write-locality fix as build_csr).
static __global__ __launch_bounds__(256) void count_deg_part_kernel(
    const int* __restrict__ dst, int* __restrict__ deg) {
    const int part = blockIdx.x & (NPART - 1);
    const int lo = part * PSIZE;
    const int hi = (part == NPART - 1) ? NODES : lo + PSIZE;
    const int group = blockIdx.x >> 3;
    const int ngroups = gridDim.x >> 3;
    int i = group * 256 + threadIdx.x;
    int stride = ngroups * 256;
    for (int e = i; e < NEDGE; e += stride) {
        int d = dst[e];
        if (d >= lo && d < hi) atomicAdd(&deg[d], 1);
    }
}

static __global__ __launch_bounds__(256) void scan_partial_kernel(
    const int* __restrict__ deg, int* __restrict__ partials) {
    __shared__ int ss[256];
    int t = threadIdx.x;
    int base = blockIdx.x * SCHUNK + t * 4;
    int s = 0;
#pragma unroll
    for (int j = 0; j < 4; ++j) {
        int i = base + j;
        if (i < NODES) s += deg[i];
    }
    ss[t] = s;
    __syncthreads();
    for (int off = 128; off > 0; off >>= 1) {
        if (t < off) ss[t] += ss[t + off];
        __syncthreads();
    }
    if (t == 0) partials[blockIdx.x] = ss[0];
}

static __global__ __launch_bounds__(128) void scan_offsets_kernel(
    const int* __restrict__ partials, int* __restrict__ block_off,
    int* __restrict__ row_ptr) {
    __shared__ int ss[128];
    int t = threadIdx.x;
    int v = (t < SBLOCKS) ? partials[t] : 0;
    ss[t] = v;
    __syncthreads();
    for (int off = 1; off < 128; off <<= 1) {
        int u = (t >= off) ? ss[t - off] : 0;
        __syncthreads();
        ss[t] += u;
        __syncthreads();
    }
    if (t < SBLOCKS) block_off[t] = ss[t] - v;  // exclusive
    if (t == 127) row_ptr[NODES] = ss[127];
}

static __global__ __launch_bounds__(256) void scan_scatter_kernel(
    const int* deg, const int* __restrict__ block_off,
    int* __restrict__ row_ptr, int* cursor) {
    __shared__ int ss[256];
    int t = threadIdx.x;
    int base = blockIdx.x * SCHUNK + t * 4;
    int d[4];
    int s = 0;
#pragma unroll
    for (int j = 0; j < 4; ++j) {
        int i = base + j;
        d[j] = (i < NODES) ? deg[i] : 0;
        s += d[j];
    }
    ss[t] = s;
    __syncthreads();
    for (int off = 1; off < 256; off <<= 1) {
        int u = (t >= off) ? ss[t - off] : 0;
        __syncthreads();
        ss[t] += u;
        __syncthreads();
    }
    int run = block_off[blockIdx.x] + ss[t] - s;
#pragma unroll
    for (int j = 0; j < 4; ++j) {
        int i = base + j;
        if (i < NODES) {
            row_ptr[i] = run;
            cursor[i] = run;
            run += d[j];
        }
    }
}

static __global__ __launch_bounds__(256) void build_csr_part_kernel(
    const int* __restrict__ src, const int* __restrict__ dst,
    int* __restrict__ cursor, int* __restrict__ col) {
    const int part = blockIdx.x & (NPART - 1);
    const int lo = part * PSIZE;
    const int hi = (part == NPART - 1) ? NODES : lo + PSIZE;
    const int group = blockIdx.x >> 3;
    const int ngroups = gridDim.x >> 3;
    int i = group * 256 + threadIdx.x;
    int stride = ngroups * 256;
    for (int e = i; e < NEDGE; e += stride) {
        int d = dst[e];
        if (d >= lo && d < hi) {
            int pos = atomicAdd(&cursor[d], 1);
            col[pos] = src[e];
        }
    }
}

// -------------------------------------------------- layer-1 MFMA dual GEMM
// U8 = fp8(X @ W1l)  (waves 0-1),  V16 = fp16(X @ W1r + b1)  (waves 2-3).

static __global__ __launch_bounds__(256) void gemm1_mfma_kernel(
    const float* __restrict__ X, const _Float16* __restrict__ WT1,
    const float* __restrict__ b1,
    unsigned char* __restrict__ U8, _Float16* __restrict__ V16) {
    __shared__ _Float16 sX[64][136];
    const int tid = threadIdx.x;
    const int row0 = blockIdx.x * 64;
    {
        int c4 = (tid & 31) * 4;
        int r0 = tid >> 5;
#pragma unroll
        for (int p = 0; p < 8; ++p) {
            int r = r0 + p * 8;
            int row = row0 + r;
            float4 v = make_float4(0.f, 0.f, 0.f, 0.f);
            if (row < NODES) v = *(const float4*)(X + (size_t)row * 128 + c4);
            sX[r][c4 + 0] = (_Float16)v.x;
            sX[r][c4 + 1] = (_Float16)v.y;
            sX[r][c4 + 2] = (_Float16)v.z;
            sX[r][c4 + 3] = (_Float16)v.w;
        }
    }
    __syncthreads();

    const int wave = tid >> 6;
    const int lane = tid & 63;
    const int l15 = lane & 15;
    const int quad = lane >> 4;

    floatx4 acc[4][4];  // [j][m]
#pragma unroll
    for (int j = 0; j < 4; ++j)
#pragma unroll
        for (int m = 0; m < 4; ++m) acc[j][m] = (floatx4){0.f, 0.f, 0.f, 0.f};

    const _Float16* Wbase = WT1 + (size_t)(wave * 64 + l15) * 128 + quad * 8;

    for (int k0 = 0; k0 < 128; k0 += 32) {
        half8 a[4];
#pragma unroll
        for (int m = 0; m < 4; ++m)
            a[m] = *(const half8*)&sX[m * 16 + l15][quad * 8 + k0];
#pragma unroll
        for (int j = 0; j < 4; ++j) {
            half8 b = *(const half8*)(Wbase + (size_t)j * 16 * 128 + k0);
#pragma unroll
            for (int m = 0; m < 4; ++m)
                acc[j][m] = __builtin_amdgcn_mfma_f32_16x16x32_f16(a[m], b, acc[j][m], 0, 0, 0);
        }
    }

    const int nbase = wave * 64 + l15;
    if (wave < 2) {
#pragma unroll
        for (int j = 0; j < 4; ++j) {
            int n = nbase + j * 16;
#pragma unroll
            for (int m = 0; m < 4; ++m)
#pragma unroll
                for (int r = 0; r < 4; ++r) {
                    int row = row0 + m * 16 + quad * 4 + r;
                    if (row < NODES)
                        U8[(size_t)row * 128 + n] = f2fp8(acc[j][m][r]);
                }
        }
    } else {
#pragma unroll
        for (int j = 0; j < 4; ++j) {
            int nn = nbase + j * 16 - 128;
            float badd = b1[nn];
#pragma unroll
            for (int m = 0; m < 4; ++m)
#pragma unroll
                for (int r = 0; r < 4; ++r) {
                    int row = row0 + m * 16 + quad * 4 + r;
                    if (row < NODES)
                        V16[(size_t)row * 128 + nn] = (_Float16)(acc[j][m][r] + badd);
                }
        }
    }
}

// -------------------------------------------------- layer-1 aggregate
// One wave per node; 4 groups of 16 lanes split the edge stream (p = s+g+4i)
// -> 16 outstanding gathers/wave (4 groups x unroll 4), zero divergence.
// Lane loads uint2 (8 fp8) of its feature slice; shfl_xor(16,32) combines
// group partials; lanes 0-15 do the 256 B epilogue (relu(mean+V) -> fp16).

static __global__ __launch_bounds__(256) void agg1_kernel(
    const unsigned char* __restrict__ U8, const int* __restrict__ row_ptr,
    const int* __restrict__ col, unsigned int* __restrict__ H32) {
    int node = (int)((blockIdx.x * 256 + threadIdx.x) >> 6);
    int lane = threadIdx.x & 63;
    if (node >= NODES) return;
    const int g = lane >> 4;
    const int l16 = lane & 15;
    int s = row_ptr[node];
    int e = row_ptr[node + 1];
    float inv = 1.0f / (float)max(e - s, 1);

    float acc[8];
#pragma unroll
    for (int i = 0; i < 8; ++i) acc[i] = 0.f;

    int p = s + g;
    for (; p + 12 < e; p += 16) {
        int c0 = col[p], c1 = col[p + 4], c2 = col[p + 8], c3 = col[p + 12];
        uint2 u0 = *(const uint2*)(U8 + (size_t)c0 * 128 + l16 * 8);
        uint2 u1 = *(const uint2*)(U8 + (size_t)c1 * 128 + l16 * 8);
        uint2 u2 = *(const uint2*)(U8 + (size_t)c2 * 128 + l16 * 8);
        uint2 u3 = *(const uint2*)(U8 + (size_t)c3 * 128 + l16 * 8);
#pragma unroll
        for (int q = 0; q < 4; ++q) {
            uint2 u = (q == 0) ? u0 : (q == 1) ? u1 : (q == 2) ? u2 : u3;
            float2 a0 = fp8x2_to_f32<false>(u.x), a1 = fp8x2_to_f32<true>(u.x);
            float2 a2 = fp8x2_to_f32<false>(u.y), a3 = fp8x2_to_f32<true>(u.y);
            acc[0] += a0.x; acc[1] += a0.y; acc[2] += a1.x; acc[3] += a1.y;
            acc[4] += a2.x; acc[5] += a2.y; acc[6] += a3.x; acc[7] += a3.y;
        }
    }
    for (; p < e; p += 4) {
        uint2 u = *(const uint2*)(U8 + (size_t)col[p] * 128 + l16 * 8);
        float2 a0 = fp8x2_to_f32<false>(u.x), a1 = fp8x2_to_f32<true>(u.x);
        float2 a2 = fp8x2_to_f32<false>(u.y), a3 = fp8x2_to_f32<true>(u.y);
        acc[0] += a0.x; acc[1] += a0.y; acc[2] += a1.x; acc[3] += a1.y;
        acc[4] += a2.x; acc[5] += a2.y; acc[6] += a3.x; acc[7] += a3.y;
    }

    // combine the 4 group partials (lanes l16, l16+16, l16+32, l16+48)
#pragma unroll
    for (int i = 0; i < 8; ++i) {
        acc[i] += __shfl_xor(acc[i], 16);
        acc[i] += __shfl_xor(acc[i], 32);
    }

    if (lane < 16) {
        uint4 vv = *(const uint4*)(H32 + (size_t)node * 64 + l16 * 4);
        float2 v0 = unpackh2(vv.x), v1 = unpackh2(vv.y);
        float2 v2 = unpackh2(vv.z), v3 = unpackh2(vv.w);
        uint4 o;
        o.x = packh2(fmaxf(acc[0] * inv + v0.x, 0.f), fmaxf(acc[1] * inv + v0.y, 0.f));
        o.y = packh2(fmaxf(acc[2] * inv + v1.x, 0.f), fmaxf(acc[3] * inv + v1.y, 0.f));
        o.z = packh2(fmaxf(acc[4] * inv + v2.x, 0.f), fmaxf(acc[5] * inv + v2.y, 0.f));
        o.w = packh2(fmaxf(acc[6] * inv + v3.x, 0.f), fmaxf(acc[7] * inv + v3.y, 0.f));
        *(uint4*)(H32 + (size_t)node * 64 + l16 * 4) = o;
    }
}

// -------------------------------------------------- layer-2 MFMA dual GEMM

static __global__ __launch_bounds__(256) void gemm2_mfma_kernel(
    const _Float16* __restrict__ H16, const _Float16* __restrict__ WT2,
    const float* __restrict__ b2,
    _Float16* __restrict__ T16, float* __restrict__ OUT) {
    __shared__ _Float16 sX[64][136];
    const int tid = threadIdx.x;
    const int row0 = blockIdx.x * 64;
    {
        int c8 = (tid & 15) * 8;
        int r0 = tid >> 4;
#pragma unroll
        for (int p = 0; p < 4; ++p) {
            int r = r0 + p * 16;
            int row = row0 + r;
            uint4 v = make_uint4(0u, 0u, 0u, 0u);
            if (row < NODES) v = *(const uint4*)(H16 + (size_t)row * 128 + c8);
            *(uint4*)&sX[r][c8] = v;
        }
    }
    __syncthreads();

    const int wave = tid >> 6;
    const int lane = tid & 63;
    const int l15 = lane & 15;
    const int quad = lane >> 4;

    floatx4 acc[2][4];
#pragma unroll
    for (int j = 0; j < 2; ++j)
#pragma unroll
        for (int m = 0; m < 4; ++m) acc[j][m] = (floatx4){0.f, 0.f, 0.f, 0.f};

    const _Float16* Wbase = WT2 + (size_t)(wave * 32 + l15) * 128 + quad * 8;

    for (int k0 = 0; k0 < 128; k0 += 32) {
        half8 a[4];
#pragma unroll
        for (int m = 0; m < 4; ++m)
            a[m] = *(const half8*)&sX[m * 16 + l15][quad * 8 + k0];
#pragma unroll
        for (int j = 0; j < 2; ++j) {
            half8 b = *(const half8*)(Wbase + (size_t)j * 16 * 128 + k0);
#pragma unroll
            for (int m = 0; m < 4; ++m)
                acc[j][m] = __builtin_amdgcn_mfma_f32_16x16x32_f16(a[m], b, acc[j][m], 0, 0, 0);
        }
    }

    const int nbase = wave * 32 + l15;
#pragma unroll
    for (int j = 0; j < 2; ++j) {
        int n = nbase + j * 16;
        bool isOut = (n >= 64);
        int nn = isOut ? n - 64 : n;
        float badd = isOut ? b2[nn] : 0.f;
#pragma unroll
        for (int m = 0; m < 4; ++m)
#pragma unroll
            for (int r = 0; r < 4; ++r) {
                int row = row0 + m * 16 + quad * 4 + r;
                if (row < NODES) {
                    float v = acc[j][m][r] + badd;
                    if (isOut) OUT[(size_t)row * 64 + nn] = v;
                    else       T16[(size_t)row * 64 + nn] = (_Float16)v;
                }
            }
    }
}

// -------------------------------------------------- layer-2 aggregate
// Same 4x16 group structure; lane loads uint2 (4 fp16) of T's 128 B row.
// Epilogue: lanes 0-15 add mean into OUT (float4 per lane, 256 B).

static __global__ __launch_bounds__(256) void agg2_kernel(
    const unsigned int* __restrict__ T32, const int* __restrict__ row_ptr,
    const int* __restrict__ col, float* __restrict__ OUT) {
    int node = (int)((blockIdx.x * 256 + threadIdx.x) >> 6);
    int lane = threadIdx.x & 63;
    if (node >= NODES) return;
    const int g = lane >> 4;
    const int l16 = lane & 15;
    int s = row_ptr[node];
    int e = row_ptr[node + 1];
    float inv = 1.0f / (float)max(e - s, 1);

    float acc[4];
#pragma unroll
    for (int i = 0; i < 4; ++i) acc[i] = 0.f;

    int p = s + g;
    for (; p + 12 < e; p += 16) {
        int c0 = col[p], c1 = col[p + 4], c2 = col[p + 8], c3 = col[p + 12];
        uint2 u0 = *(const uint2*)(T32 + (size_t)c0 * 32 + l16 * 2);
        uint2 u1 = *(const uint2*)(T32 + (size_t)c1 * 32 + l16 * 2);
        uint2 u2 = *(const uint2*)(T32 + (size_t)c2 * 32 + l16 * 2);
        uint2 u3 = *(const uint2*)(T32 + (size_t)c3 * 32 + l16 * 2);
#pragma unroll
        for (int q = 0; q < 4; ++q) {
            uint2 u = (q == 0) ? u0 : (q == 1) ? u1 : (q == 2) ? u2 : u3;
            float2 a0 = unpackh2(u.x), a1 = unpackh2(u.y);
            acc[0] += a0.x; acc[1] += a0.y; acc[2] += a1.x; acc[3] += a1.y;
        }
    }
    for (; p < e; p += 4) {
        uint2 u = *(const uint2*)(T32 + (size_t)col[p] * 32 + l16 * 2);
        float2 a0 = unpackh2(u.x), a1 = unpackh2(u.y);
        acc[0] += a0.x; acc[1] += a0.y; acc[2] += a1.x; acc[3] += a1.y;
    }

#pragma unroll
    for (int i = 0; i < 4; ++i) {
        acc[i] += __shfl_xor(acc[i], 16);
        acc[i] += __shfl_xor(acc[i], 32);
    }

    if (lane < 16) {
        float4 o = *(float4*)(OUT + (size_t)node * 64 + l16 * 4);
        o.x += acc[0] * inv;
        o.y += acc[1] * inv;
        o.z += acc[2] * inv;
        o.w += acc[3] * inv;
        *(float4*)(OUT + (size_t)node * 64 + l16 * 4) = o;
    }
}

// ---------------------------------------------------------------- launch

extern "C" void kernel_launch(void* const* d_in, const int* in_sizes, int n_in,
                              void* d_out, int out_size, void* d_ws, size_t ws_size,
                              hipStream_t stream) {
    const float* x   = (const float*)d_in[0];
    const float* W1l = (const float*)d_in[1];
    const float* b1  = (const float*)d_in[2];
    const float* W1r = (const float*)d_in[3];
    const float* W2l = (const float*)d_in[4];
    const float* b2  = (const float*)d_in[5];
    const float* W2r = (const float*)d_in[6];
    const int*   ei  = (const int*)d_in[7];
    const int* esrc = ei;          // edge_index[0]
    const int* edst = ei + NEDGE;  // edge_index[1]
    float* out = (float*)d_out;

    // ws layout — ~45.3 MB (well inside the proven 58.4 MB envelope).
    char* ws = (char*)d_ws;
    size_t off = 0;
    int* row_ptr  = (int*)(ws + off); off += (((size_t)(NODES + 1) * 4) + 255) & ~(size_t)255;
    int* col      = (int*)(ws + off); off += (size_t)NEDGE * 4;
    int* partials = (int*)(ws + off); off += 512;
    int* blockoff = (int*)(ws + off); off += 512;
    _Float16* WT1 = (_Float16*)(ws + off); off += 256 * 128 * 2;
    _Float16* WT2 = (_Float16*)(ws + off); off += 128 * 128 * 2;
    unsigned char* U8 = (unsigned char*)(ws + off); off += (size_t)NODES * 128;
    _Float16* V16 = (_Float16*)(ws + off); off += (size_t)NODES * 128 * 2;
    int* cursor = (int*)U8;            // deg/cursor alias U8 (dead until gemm1)
    _Float16* T16 = (_Float16*)U8;     // T aliases U8 (dead after agg1)

    // ---- weight conversion + CSR build
    wconv_kernel<<<192, 256, 0, stream>>>(W1l, W1r, W2l, W2r, WT1, WT2);
    zero_int_kernel<<<256, 256, 0, stream>>>(cursor, NODES);
    count_deg_part_kernel<<<2048, 256, 0, stream>>>(edst, cursor);
    scan_partial_kernel<<<SBLOCKS, 256, 0, stream>>>(cursor, partials);
    scan_offsets_kernel<<<1, 128, 0, stream>>>(partials, blockoff, row_ptr);
    scan_scatter_kernel<<<SBLOCKS, 256, 0, stream>>>(cursor, blockoff, row_ptr, cursor);
    build_csr_part_kernel<<<2048, 256, 0, stream>>>(esrc, edst, cursor, col);

    const int gemm_grid = (NODES + 63) / 64;  // 1563
    const int agg_grid  = (NODES + 3) / 4;    // one wave per node

    // ---- layer 1
    gemm1_mfma_kernel<<<gemm_grid, 256, 0, stream>>>(x, WT1, b1, U8, V16);
    agg1_kernel<<<agg_grid, 256, 0, stream>>>(U8, row_ptr, col, (unsigned int*)V16);

    // ---- layer 2 (H = V16 in place)
    gemm2_mfma_kernel<<<gemm_grid, 256, 0, stream>>>(V16, WT2, b2, T16, out);
    agg2_kernel<<<agg_grid, 256, 0, stream>>>(
        (const unsigned int*)T16, row_ptr, col, out);
}

// Round 10
// 417.310 us; speedup vs baseline: 3.3480x; 1.0045x over previous
//
#include <hip/hip_runtime.h>

#define NODES 100000
#define NEDGE 1600000
#define SCHUNK 1024
#define SBLOCKS ((NODES + SCHUNK - 1) / SCHUNK)  // 98
#define NPART 8
#define PSIZE (NODES / NPART)  // 12500

typedef _Float16 half8 __attribute__((ext_vector_type(8)));
typedef float floatx4 __attribute__((ext_vector_type(4)));
typedef float floatx2 __attribute__((ext_vector_type(2)));

// ------------------------------------------------------------ fp16 helpers

static __device__ __forceinline__ unsigned int packh2(float a, float b) {
    union { _Float16 h; unsigned short s; } x, y;
    x.h = (_Float16)a; y.h = (_Float16)b;
    return (unsigned int)x.s | ((unsigned int)y.s << 16);
}
static __device__ __forceinline__ float2 unpackh2(unsigned int u) {
    union { unsigned short s; _Float16 h; } x, y;
    x.s = (unsigned short)(u & 0xffffu);
    y.s = (unsigned short)(u >> 16);
    return make_float2((float)x.h, (float)y.h);
}

// ------------------------------------------------------------ fp8 helpers
// Word-select of cvt_pk_f32_fp8 must be an immediate -> template param.

static __device__ __forceinline__ unsigned char f2fp8(float x) {
    return (unsigned char)(__builtin_amdgcn_cvt_pk_fp8_f32(x, x, 0, false) & 0xff);
}
template <bool HI>
static __device__ __forceinline__ float2 fp8x2_to_f32(unsigned int u) {
    floatx2 r = __builtin_amdgcn_cvt_pk_f32_fp8(u, HI);
    return make_float2(r.x, r.y);
}

// ------------------------------------------- weight convert (fp32 -> fp16^T)

static __global__ __launch_bounds__(256) void wconv_kernel(
    const float* __restrict__ W1l, const float* __restrict__ W1r,
    const float* __restrict__ W2l, const float* __restrict__ W2r,
    _Float16* __restrict__ WT1, _Float16* __restrict__ WT2) {
    int idx = blockIdx.x * 256 + threadIdx.x;
    if (idx < 256 * 128) {
        int n = idx >> 7, k = idx & 127;
        float v = (n < 128) ? W1l[k * 128 + n] : W1r[k * 128 + (n - 128)];
        WT1[n * 128 + k] = (_Float16)v;
    } else if (idx < 256 * 128 + 128 * 128) {
        int i2 = idx - 256 * 128;
        int n = i2 >> 7, k = i2 & 127;
        float v = (n < 64) ? W2l[k * 64 + n] : W2r[k * 64 + (n - 64)];
        WT2[n * 128 + k] = (_Float16)v;
    }
}

// ---------------------------------------------------------------- CSR build

static __global__ void zero_int_kernel(int* __restrict__ p, int n) {
    int i = blockIdx.x * blockDim.x + threadIdx.x;
    int stride = gridDim.x * blockDim.x;
    for (; i < n; i += stride) p[i] = 0;
}

// XCD-partitioned degree count.  nt loads keep the streaming dst[] out of
// L2 so the deg/cursor lines (and later col lines) stay resident.
static __global__ __launch_bounds__(256) void count_deg_part_kernel(
    const int* __restrict__ dst, int* __restrict__ deg) {
    const int part = blockIdx.x & (NPART - 1);
    const int lo = part * PSIZE;
    const int hi = (part == NPART - 1) ? NODES : lo + PSIZE;
    const int group = blockIdx.x >> 3;
    const int ngroups = gridDim.x >> 3;
    int i = group * 256 + threadIdx.x;
    int stride = ngroups * 256;
    for (int e = i; e < NEDGE; e += stride) {
        int d = __builtin_nontemporal_load(dst + e);
        if (d >= lo && d < hi) atomicAdd(&deg[d], 1);
    }
}

static __global__ __launch_bounds__(256) void scan_partial_kernel(
    const int* __restrict__ deg, int* __restrict__ partials) {
    __shared__ int ss[256];
    int t = threadIdx.x;
    int base = blockIdx.x * SCHUNK + t * 4;
    int s = 0;
#pragma unroll
    for (int j = 0; j < 4; ++j) {
        int i = base + j;
        if (i < NODES) s += deg[i];
    }
    ss[t] = s;
    __syncthreads();
    for (int off = 128; off > 0; off >>= 1) {
        if (t < off) ss[t] += ss[t + off];
        __syncthreads();
    }
    if (t == 0) partials[blockIdx.x] = ss[0];
}

static __global__ __launch_bounds__(128) void scan_offsets_kernel(
    const int* __restrict__ partials, int* __restrict__ block_off,
    int* __restrict__ row_ptr) {
    __shared__ int ss[128];
    int t = threadIdx.x;
    int v = (t < SBLOCKS) ? partials[t] : 0;
    ss[t] = v;
    __syncthreads();
    for (int off = 1; off < 128; off <<= 1) {
        int u = (t >= off) ? ss[t - off] : 0;
        __syncthreads();
        ss[t] += u;
        __syncthreads();
    }
    if (t < SBLOCKS) block_off[t] = ss[t] - v;  // exclusive
    if (t == 127) row_ptr[NODES] = ss[127];
}

static __global__ __launch_bounds__(256) void scan_scatter_kernel(
    const int* deg, const int* __restrict__ block_off,
    int* __restrict__ row_ptr, int* cursor) {
    __shared__ int ss[256];
    int t = threadIdx.x;
    int base = blockIdx.x * SCHUNK + t * 4;
    int d[4];
    int s = 0;
#pragma unroll
    for (int j = 0; j < 4; ++j) {
        int i = base + j;
        d[j] = (i < NODES) ? deg[i] : 0;
        s += d[j];
    }
    ss[t] = s;
    __syncthreads();
    for (int off = 1; off < 256; off <<= 1) {
        int u = (t >= off) ? ss[t - off] : 0;
        __syncthreads();
        ss[t] += u;
        __syncthreads();
    }
    int run = block_off[blockIdx.x] + ss[t] - s;
#pragma unroll
    for (int j = 0; j < 4; ++j) {
        int i = base + j;
        if (i < NODES) {
            row_ptr[i] = run;
            cursor[i] = run;
            run += d[j];
        }
    }
}

// XCD-partitioned CSR fill.  nt loads on the streamed src/dst prevent them
// evicting the partition's 0.8 MB col slice from L2 (R9: 73 MB WRITE from
// partial-line writebacks; theory = streaming eviction).
static __global__ __launch_bounds__(256) void build_csr_part_kernel(
    const int* __restrict__ src, const int* __restrict__ dst,
    int* __restrict__ cursor, int* __restrict__ col) {
    const int part = blockIdx.x & (NPART - 1);
    const int lo = part * PSIZE;
    const int hi = (part == NPART - 1) ? NODES : lo + PSIZE;
    const int group = blockIdx.x >> 3;
    const int ngroups = gridDim.x >> 3;
    int i = group * 256 + threadIdx.x;
    int stride = ngroups * 256;
    for (int e = i; e < NEDGE; e += stride) {
        int d = __builtin_nontemporal_load(dst + e);
        if (d >= lo && d < hi) {
            int sv = __builtin_nontemporal_load(src + e);
            int pos = atomicAdd(&cursor[d], 1);
            col[pos] = sv;
        }
    }
}

// -------------------------------------------------- layer-1 MFMA dual GEMM
// U8 = fp8(X @ W1l)  (waves 0-1),  V16 = fp16(X @ W1r + b1)  (waves 2-3).

static __global__ __launch_bounds__(256) void gemm1_mfma_kernel(
    const float* __restrict__ X, const _Float16* __restrict__ WT1,
    const float* __restrict__ b1,
    unsigned char* __restrict__ U8, _Float16* __restrict__ V16) {
    __shared__ _Float16 sX[64][136];
    const int tid = threadIdx.x;
    const int row0 = blockIdx.x * 64;
    {
        int c4 = (tid & 31) * 4;
        int r0 = tid >> 5;
#pragma unroll
        for (int p = 0; p < 8; ++p) {
            int r = r0 + p * 8;
            int row = row0 + r;
            float4 v = make_float4(0.f, 0.f, 0.f, 0.f);
            if (row < NODES) v = *(const float4*)(X + (size_t)row * 128 + c4);
            sX[r][c4 + 0] = (_Float16)v.x;
            sX[r][c4 + 1] = (_Float16)v.y;
            sX[r][c4 + 2] = (_Float16)v.z;
            sX[r][c4 + 3] = (_Float16)v.w;
        }
    }
    __syncthreads();

    const int wave = tid >> 6;
    const int lane = tid & 63;
    const int l15 = lane & 15;
    const int quad = lane >> 4;

    floatx4 acc[4][4];  // [j][m]
#pragma unroll
    for (int j = 0; j < 4; ++j)
#pragma unroll
        for (int m = 0; m < 4; ++m) acc[j][m] = (floatx4){0.f, 0.f, 0.f, 0.f};

    const _Float16* Wbase = WT1 + (size_t)(wave * 64 + l15) * 128 + quad * 8;

    for (int k0 = 0; k0 < 128; k0 += 32) {
        half8 a[4];
#pragma unroll
        for (int m = 0; m < 4; ++m)
            a[m] = *(const half8*)&sX[m * 16 + l15][quad * 8 + k0];
#pragma unroll
        for (int j = 0; j < 4; ++j) {
            half8 b = *(const half8*)(Wbase + (size_t)j * 16 * 128 + k0);
#pragma unroll
            for (int m = 0; m < 4; ++m)
                acc[j][m] = __builtin_amdgcn_mfma_f32_16x16x32_f16(a[m], b, acc[j][m], 0, 0, 0);
        }
    }

    const int nbase = wave * 64 + l15;
    if (wave < 2) {
#pragma unroll
        for (int j = 0; j < 4; ++j) {
            int n = nbase + j * 16;
#pragma unroll
            for (int m = 0; m < 4; ++m)
#pragma unroll
                for (int r = 0; r < 4; ++r) {
                    int row = row0 + m * 16 + quad * 4 + r;
                    if (row < NODES)
                        U8[(size_t)row * 128 + n] = f2fp8(acc[j][m][r]);
                }
        }
    } else {
#pragma unroll
        for (int j = 0; j < 4; ++j) {
            int nn = nbase + j * 16 - 128;
            float badd = b1[nn];
#pragma unroll
            for (int m = 0; m < 4; ++m)
#pragma unroll
                for (int r = 0; r < 4; ++r) {
                    int row = row0 + m * 16 + quad * 4 + r;
                    if (row < NODES)
                        V16[(size_t)row * 128 + nn] = (_Float16)(acc[j][m][r] + badd);
                }
        }
    }
}

// -------------------------------------------------- layer-1 aggregate
// One wave per node; 4 groups of 16 lanes split the edge stream (p = s+g+4i)
// -> 16 outstanding gathers/wave, zero divergence.  shfl_xor(16,32)
// combines group partials; lanes 0-15 do the 256 B epilogue.

static __global__ __launch_bounds__(256) void agg1_kernel(
    const unsigned char* __restrict__ U8, const int* __restrict__ row_ptr,
    const int* __restrict__ col, unsigned int* __restrict__ H32) {
    int node = (int)((blockIdx.x * 256 + threadIdx.x) >> 6);
    int lane = threadIdx.x & 63;
    if (node >= NODES) return;
    const int g = lane >> 4;
    const int l16 = lane & 15;
    int s = row_ptr[node];
    int e = row_ptr[node + 1];
    float inv = 1.0f / (float)max(e - s, 1);

    float acc[8];
#pragma unroll
    for (int i = 0; i < 8; ++i) acc[i] = 0.f;

    int p = s + g;
    for (; p + 12 < e; p += 16) {
        int c0 = col[p], c1 = col[p + 4], c2 = col[p + 8], c3 = col[p + 12];
        uint2 u0 = *(const uint2*)(U8 + (size_t)c0 * 128 + l16 * 8);
        uint2 u1 = *(const uint2*)(U8 + (size_t)c1 * 128 + l16 * 8);
        uint2 u2 = *(const uint2*)(U8 + (size_t)c2 * 128 + l16 * 8);
        uint2 u3 = *(const uint2*)(U8 + (size_t)c3 * 128 + l16 * 8);
#pragma unroll
        for (int q = 0; q < 4; ++q) {
            uint2 u = (q == 0) ? u0 : (q == 1) ? u1 : (q == 2) ? u2 : u3;
            float2 a0 = fp8x2_to_f32<false>(u.x), a1 = fp8x2_to_f32<true>(u.x);
            float2 a2 = fp8x2_to_f32<false>(u.y), a3 = fp8x2_to_f32<true>(u.y);
            acc[0] += a0.x; acc[1] += a0.y; acc[2] += a1.x; acc[3] += a1.y;
            acc[4] += a2.x; acc[5] += a2.y; acc[6] += a3.x; acc[7] += a3.y;
        }
    }
    for (; p < e; p += 4) {
        uint2 u = *(const uint2*)(U8 + (size_t)col[p] * 128 + l16 * 8);
        float2 a0 = fp8x2_to_f32<false>(u.x), a1 = fp8x2_to_f32<true>(u.x);
        float2 a2 = fp8x2_to_f32<false>(u.y), a3 = fp8x2_to_f32<true>(u.y);
        acc[0] += a0.x; acc[1] += a0.y; acc[2] += a1.x; acc[3] += a1.y;
        acc[4] += a2.x; acc[5] += a2.y; acc[6] += a3.x; acc[7] += a3.y;
    }

#pragma unroll
    for (int i = 0; i < 8; ++i) {
        acc[i] += __shfl_xor(acc[i], 16);
        acc[i] += __shfl_xor(acc[i], 32);
    }

    if (lane < 16) {
        uint4 vv = *(const uint4*)(H32 + (size_t)node * 64 + l16 * 4);
        float2 v0 = unpackh2(vv.x), v1 = unpackh2(vv.y);
        float2 v2 = unpackh2(vv.z), v3 = unpackh2(vv.w);
        uint4 o;
        o.x = packh2(fmaxf(acc[0] * inv + v0.x, 0.f), fmaxf(acc[1] * inv + v0.y, 0.f));
        o.y = packh2(fmaxf(acc[2] * inv + v1.x, 0.f), fmaxf(acc[3] * inv + v1.y, 0.f));
        o.z = packh2(fmaxf(acc[4] * inv + v2.x, 0.f), fmaxf(acc[5] * inv + v2.y, 0.f));
        o.w = packh2(fmaxf(acc[6] * inv + v3.x, 0.f), fmaxf(acc[7] * inv + v3.y, 0.f));
        *(uint4*)(H32 + (size_t)node * 64 + l16 * 4) = o;
    }
}

// -------------------------------------------------- layer-2 MFMA dual GEMM

static __global__ __launch_bounds__(256) void gemm2_mfma_kernel(
    const _Float16* __restrict__ H16, const _Float16* __restrict__ WT2,
    const float* __restrict__ b2,
    _Float16* __restrict__ T16, float* __restrict__ OUT) {
    __shared__ _Float16 sX[64][136];
    const int tid = threadIdx.x;
    const int row0 = blockIdx.x * 64;
    {
        int c8 = (tid & 15) * 8;
        int r0 = tid >> 4;
#pragma unroll
        for (int p = 0; p < 4; ++p) {
            int r = r0 + p * 16;
            int row = row0 + r;
            uint4 v = make_uint4(0u, 0u, 0u, 0u);
            if (row < NODES) v = *(const uint4*)(H16 + (size_t)row * 128 + c8);
            *(uint4*)&sX[r][c8] = v;
        }
    }
    __syncthreads();

    const int wave = tid >> 6;
    const int lane = tid & 63;
    const int l15 = lane & 15;
    const int quad = lane >> 4;

    floatx4 acc[2][4];
#pragma unroll
    for (int j = 0; j < 2; ++j)
#pragma unroll
        for (int m = 0; m < 4; ++m) acc[j][m] = (floatx4){0.f, 0.f, 0.f, 0.f};

    const _Float16* Wbase = WT2 + (size_t)(wave * 32 + l15) * 128 + quad * 8;

    for (int k0 = 0; k0 < 128; k0 += 32) {
        half8 a[4];
#pragma unroll
        for (int m = 0; m < 4; ++m)
            a[m] = *(const half8*)&sX[m * 16 + l15][quad * 8 + k0];
#pragma unroll
        for (int j = 0; j < 2; ++j) {
            half8 b = *(const half8*)(Wbase + (size_t)j * 16 * 128 + k0);
#pragma unroll
            for (int m = 0; m < 4; ++m)
                acc[j][m] = __builtin_amdgcn_mfma_f32_16x16x32_f16(a[m], b, acc[j][m], 0, 0, 0);
        }
    }

    const int nbase = wave * 32 + l15;
#pragma unroll
    for (int j = 0; j < 2; ++j) {
        int n = nbase + j * 16;
        bool isOut = (n >= 64);
        int nn = isOut ? n - 64 : n;
        float badd = isOut ? b2[nn] : 0.f;
#pragma unroll
        for (int m = 0; m < 4; ++m)
#pragma unroll
            for (int r = 0; r < 4; ++r) {
                int row = row0 + m * 16 + quad * 4 + r;
                if (row < NODES) {
                    float v = acc[j][m][r] + badd;
                    if (isOut) OUT[(size_t)row * 64 + nn] = v;
                    else       T16[(size_t)row * 64 + nn] = (_Float16)v;
                }
            }
    }
}

// -------------------------------------------------- layer-2 aggregate

static __global__ __launch_bounds__(256) void agg2_kernel(
    const unsigned int* __restrict__ T32, const int* __restrict__ row_ptr,
    const int* __restrict__ col, float* __restrict__ OUT) {
    int node = (int)((blockIdx.x * 256 + threadIdx.x) >> 6);
    int lane = threadIdx.x & 63;
    if (node >= NODES) return;
    const int g = lane >> 4;
    const int l16 = lane & 15;
    int s = row_ptr[node];
    int e = row_ptr[node + 1];
    float inv = 1.0f / (float)max(e - s, 1);

    float acc[4];
#pragma unroll
    for (int i = 0; i < 4; ++i) acc[i] = 0.f;

    int p = s + g;
    for (; p + 12 < e; p += 16) {
        int c0 = col[p], c1 = col[p + 4], c2 = col[p + 8], c3 = col[p + 12];
        uint2 u0 = *(const uint2*)(T32 + (size_t)c0 * 32 + l16 * 2);
        uint2 u1 = *(const uint2*)(T32 + (size_t)c1 * 32 + l16 * 2);
        uint2 u2 = *(const uint2*)(T32 + (size_t)c2 * 32 + l16 * 2);
        uint2 u3 = *(const uint2*)(T32 + (size_t)c3 * 32 + l16 * 2);
#pragma unroll
        for (int q = 0; q < 4; ++q) {
            uint2 u = (q == 0) ? u0 : (q == 1) ? u1 : (q == 2) ? u2 : u3;
            float2 a0 = unpackh2(u.x), a1 = unpackh2(u.y);
            acc[0] += a0.x; acc[1] += a0.y; acc[2] += a1.x; acc[3] += a1.y;
        }
    }
    for (; p < e; p += 4) {
        uint2 u = *(const uint2*)(T32 + (size_t)col[p] * 32 + l16 * 2);
        float2 a0 = unpackh2(u.x), a1 = unpackh2(u.y);
        acc[0] += a0.x; acc[1] += a0.y; acc[2] += a1.x; acc[3] += a1.y;
    }

#pragma unroll
    for (int i = 0; i < 4; ++i) {
        acc[i] += __shfl_xor(acc[i], 16);
        acc[i] += __shfl_xor(acc[i], 32);
    }

    if (lane < 16) {
        float4 o = *(float4*)(OUT + (size_t)node * 64 + l16 * 4);
        o.x += acc[0] * inv;
        o.y += acc[1] * inv;
        o.z += acc[2] * inv;
        o.w += acc[3] * inv;
        *(float4*)(OUT + (size_t)node * 64 + l16 * 4) = o;
    }
}

// ---------------------------------------------------------------- launch

extern "C" void kernel_launch(void* const* d_in, const int* in_sizes, int n_in,
                              void* d_out, int out_size, void* d_ws, size_t ws_size,
                              hipStream_t stream) {
    const float* x   = (const float*)d_in[0];
    const float* W1l = (const float*)d_in[1];
    const float* b1  = (const float*)d_in[2];
    const float* W1r = (const float*)d_in[3];
    const float* W2l = (const float*)d_in[4];
    const float* b2  = (const float*)d_in[5];
    const float* W2r = (const float*)d_in[6];
    const int*   ei  = (const int*)d_in[7];
    const int* esrc = ei;          // edge_index[0]
    const int* edst = ei + NEDGE;  // edge_index[1]
    float* out = (float*)d_out;

    // ws layout — ~45.3 MB (well inside the proven 58.4 MB envelope).
    char* ws = (char*)d_ws;
    size_t off = 0;
    int* row_ptr  = (int*)(ws + off); off += (((size_t)(NODES + 1) * 4) + 255) & ~(size_t)255;
    int* col      = (int*)(ws + off); off += (size_t)NEDGE * 4;
    int* partials = (int*)(ws + off); off += 512;
    int* blockoff = (int*)(ws + off); off += 512;
    _Float16* WT1 = (_Float16*)(ws + off); off += 256 * 128 * 2;
    _Float16* WT2 = (_Float16*)(ws + off); off += 128 * 128 * 2;
    unsigned char* U8 = (unsigned char*)(ws + off); off += (size_t)NODES * 128;
    _Float16* V16 = (_Float16*)(ws + off); off += (size_t)NODES * 128 * 2;
    int* cursor = (int*)U8;            // deg/cursor alias U8 (dead until gemm1)
    _Float16* T16 = (_Float16*)U8;     // T aliases U8 (dead after agg1)

    // ---- weight conversion + CSR build
    wconv_kernel<<<192, 256, 0, stream>>>(W1l, W1r, W2l, W2r, WT1, WT2);
    zero_int_kernel<<<256, 256, 0, stream>>>(cursor, NODES);
    count_deg_part_kernel<<<2048, 256, 0, stream>>>(edst, cursor);
    scan_partial_kernel<<<SBLOCKS, 256, 0, stream>>>(cursor, partials);
    scan_offsets_kernel<<<1, 128, 0, stream>>>(partials, blockoff, row_ptr);
    scan_scatter_kernel<<<SBLOCKS, 256, 0, stream>>>(cursor, blockoff, row_ptr, cursor);
    build_csr_part_kernel<<<2048, 256, 0, stream>>>(esrc, edst, cursor, col);

    const int gemm_grid = (NODES + 63) / 64;  // 1563
    const int agg_grid  = (NODES + 3) / 4;    // one wave per node

    // ---- layer 1
    gemm1_mfma_kernel<<<gemm_grid, 256, 0, stream>>>(x, WT1, b1, U8, V16);
    agg1_kernel<<<agg_grid, 256, 0, stream>>>(U8, row_ptr, col, (unsigned int*)V16);

    // ---- layer 2 (H = V16 in place)
    gemm2_mfma_kernel<<<gemm_grid, 256, 0, stream>>>(V16, WT2, b2, T16, out);
    agg2_kernel<<<agg_grid, 256, 0, stream>>>(
        (const unsigned int*)T16, row_ptr, col, out);
}